// Round 8
// baseline (528.915 us; speedup 1.0000x reference)
//
#include <hip/hip_runtime.h>
#include <cmath>

// ============================================================================
// AutoregressiveGroupQuerySelfAttention  (B=2, S=2048, H=2048, nH=16, D=128)
//
// Round 12: gemm_qk K-loop ported to the m201-style phase template.
//  - Per K-step: 4 phases (ks0-Q, ks0-K, ks1-Q, ks1-K), each
//    {ds_read cluster -> s_barrier -> lgkmcnt(0) -> setprio(1) 12 MFMAs
//    setprio(0) -> s_barrier}. MFMA clusters are pure-register; ds_read
//    latency hides under barrier skew + sibling wave's MFMA cluster.
//  - Bulk stage(t+1) + counted vmcnt(8) skeleton kept verbatim (full-step
//    prefetch cover already proven). Single variable vs R11: compute
//    interleave only.
//  - gemm8 (1-term), attn, aux kernels unchanged.
// ============================================================================

typedef unsigned short u16;
typedef __attribute__((ext_vector_type(4))) float  f32x4;
typedef __attribute__((ext_vector_type(16))) float f32x16;
typedef __attribute__((ext_vector_type(4))) float  float4v;
typedef __attribute__((ext_vector_type(4))) unsigned short u16x4;
typedef __attribute__((ext_vector_type(8))) unsigned short u16x8;
typedef __attribute__((ext_vector_type(8))) short s16x8;

__device__ __forceinline__ u16 f2bf(float f) {
  unsigned u = __float_as_uint(f);
  u += 0x7FFFu + ((u >> 16) & 1u);            // RNE; inputs are finite
  return (u16)(u >> 16);
}
__device__ __forceinline__ float bf2f(u16 h) {
  return __uint_as_float(((unsigned)h) << 16);
}
__device__ __forceinline__ f32x16 MFMA32(s16x8 a, s16x8 b, f32x16 c) {
  return __builtin_amdgcn_mfma_f32_32x32x16_bf16(a, b, c, 0, 0, 0);
}
__device__ __forceinline__ unsigned cvtpk_bf16(float lo, float hi) {
  unsigned r;
  asm("v_cvt_pk_bf16_f32 %0, %1, %2" : "=v"(r) : "v"(lo), "v"(hi));
  return r;
}
// async global->LDS, 16B per lane; LDS dest = wave-uniform base + lane*16
__device__ __forceinline__ void gld16(const void* g, void* s) {
  __builtin_amdgcn_global_load_lds(
      (const __attribute__((address_space(1))) void*)g,
      (__attribute__((address_space(3))) void*)s, 16, 0, 0);
}

// ---------------------------------------------------------------------------
// fp32 -> bf16 hi (+ optional lo residual).  n4 = element count / 4.
// ---------------------------------------------------------------------------
__global__ void split_bf16(const float* __restrict__ src, u16* __restrict__ hi,
                           u16* __restrict__ lo, int n4) {
  int i = blockIdx.x * 256 + threadIdx.x;
  if (i >= n4) return;
  float4v v = ((const float4v*)src)[i];
  u16x4 hv, lv;
#pragma unroll
  for (int j = 0; j < 4; ++j) {
    float f = v[j];
    u16 h = f2bf(f);
    hv[j] = h;
    lv[j] = f2bf(f - bf2f(h));
  }
  ((u16x4*)hi)[i] = hv;
  if (lo) ((u16x4*)lo)[i] = lv;
}

// ---------------------------------------------------------------------------
// RoPE tables in fp64.
// ---------------------------------------------------------------------------
__global__ void rope_tab(float* __restrict__ cosT, float* __restrict__ sinT) {
  int idx = blockIdx.x * 256 + threadIdx.x;   // 2048*64
  int i = idx & 63, s = idx >> 6;
  double invf = pow(10000.0, -(double)i / 64.0);
  double ang = (double)s * invf;
  cosT[idx] = (float)cos(ang);
  sinT[idx] = (float)sin(ang);
}

// ---------------------------------------------------------------------------
// gemm_qk: fused Q/K projection.  Q = x Wq^T (RoPE, *qscale), K = x Wk^T
// (RoPE). Split-precision 3-term on both. 256x128 tile, BK=32, 512 thr =
// 8 waves (wm=w>>1, wn=w&1), per-wave 64x64 per output.
// LDS buffer (u16): A_hi[0,8192) A_lo[8192,16384) Bq_hi[16384,20480)
// Bq_lo[20480,24576) Bk_hi[24576,28672) Bk_lo[28672,32768). 2 bufs = 128KB.
// K-loop: bulk stage(t+1) + vmcnt(8), then 4 phases per step (m201 template):
// {ds_read cluster -> s_barrier -> lgkmcnt(0) -> 12 MFMAs (setprio) ->
//  s_barrier}. 16B-chunk involution swizzle; XCD remap (grid 16x16).
// ---------------------------------------------------------------------------
__global__ __launch_bounds__(512, 2)
void gemm_qk(const u16* __restrict__ xh, const u16* __restrict__ xl,
             const u16* __restrict__ Wqh, const u16* __restrict__ Wql,
             const u16* __restrict__ Wkh, const u16* __restrict__ Wkl,
             u16* __restrict__ Qh, u16* __restrict__ Ql,
             u16* __restrict__ Kh, u16* __restrict__ Kl,
             const float* __restrict__ cosT, const float* __restrict__ sinT,
             float qscale, int M, int N, int K) {
  __shared__ u16 SM[2 * 32768];                 // 128 KB
  const int t = threadIdx.x;
  const int w = t >> 6, lane = t & 63;
  const int l31 = lane & 31, hi = lane >> 5;
  const int wm = w >> 1, wn = w & 1;

  // ---- XCD-locality remap (grid.x = 16 -> 2 bn per XCD) ----
  const int bid = (int)blockIdx.x + 16 * (int)blockIdx.y;
  const int xcd = bid & 7, slot = bid >> 3;
  const int bn = 2 * xcd + (slot & 1);
  const int bm = slot >> 1;

  const size_t arow0 = (size_t)bm * 256, brow0 = (size_t)bn * 128;

  // ---- staging: linear LDS dest, pre-swizzled global source ----
  const int pA0 = 128 * w + lane;          // 16B-chunk index within A region
  const int pA1 = pA0 + 64;
  const int pB0 = 64 * w + lane;
  const int qA0 = pA0 ^ ((pA0 >> 3) & 7);
  const int qA1 = pA1 ^ ((pA1 >> 3) & 7);
  const int qB0 = pB0 ^ ((pB0 >> 3) & 7);
  const size_t gA0 = (arow0 + (qA0 >> 2)) * (size_t)K + (qA0 & 3) * 8;
  const size_t gA1 = (arow0 + (qA1 >> 2)) * (size_t)K + (qA1 & 3) * 8;
  const size_t gB0 = (brow0 + (qB0 >> 2)) * (size_t)K + (qB0 & 3) * 8;

  auto stage = [&](int k0, int bp) {
    u16* P = &SM[bp * 32768];
    gld16(&xh[gA0 + k0], P + 1024 * w);
    gld16(&xh[gA1 + k0], P + 1024 * w + 512);
    gld16(&xl[gA0 + k0], P + 8192 + 1024 * w);
    gld16(&xl[gA1 + k0], P + 8192 + 1024 * w + 512);
    gld16(&Wqh[gB0 + k0], P + 16384 + 512 * w);
    gld16(&Wql[gB0 + k0], P + 20480 + 512 * w);
    gld16(&Wkh[gB0 + k0], P + 24576 + 512 * w);
    gld16(&Wkl[gB0 + k0], P + 28672 + 512 * w);
  };

  // ---- swizzled read offsets (u16 units, within region) ----
  auto aoff = [&](int fm, int ks) {
    int q = ((64 * wm + 32 * fm + l31) << 2) | (2 * ks + hi);
    q ^= (q >> 3) & 7;
    return q * 8;
  };
  auto boff = [&](int fn, int ks) {
    int q = ((32 * wn + 64 * fn + l31) << 2) | (2 * ks + hi);
    q ^= (q >> 3) & 7;
    return q * 8;
  };

  f32x16 accq[2][2], acck[2][2];
#pragma unroll
  for (int fm = 0; fm < 2; ++fm)
#pragma unroll
    for (int fn = 0; fn < 2; ++fn)
#pragma unroll
      for (int r = 0; r < 16; ++r) { accq[fm][fn][r] = 0.f; acck[fm][fn][r] = 0.f; }

  const int NK = K >> 5;
  stage(0, 0);
  int bp = 0;
  for (int kt = 0; kt < NK; ++kt) {
    if (kt + 1 < NK) {
      stage((kt + 1) * 32, bp ^ 1);
      asm volatile("s_waitcnt vmcnt(8)" ::: "memory");
    } else {
      asm volatile("s_waitcnt vmcnt(0)" ::: "memory");
    }
    __builtin_amdgcn_sched_barrier(0);
    __builtin_amdgcn_s_barrier();
    __builtin_amdgcn_sched_barrier(0);

    const u16* P = &SM[bp * 32768];
#pragma unroll
    for (int ks = 0; ks < 2; ++ks) {
      s16x8 a_h[2], a_l[2], b_h[2], b_l[2];
      // ======== phase Q(ks): read A + Bq, barrier, MFMA cluster ========
#pragma unroll
      for (int fm = 0; fm < 2; ++fm) {
        a_h[fm] = *(const s16x8*)&P[aoff(fm, ks)];
        a_l[fm] = *(const s16x8*)&P[8192 + aoff(fm, ks)];
      }
#pragma unroll
      for (int fn = 0; fn < 2; ++fn) {
        b_h[fn] = *(const s16x8*)&P[16384 + boff(fn, ks)];
        b_l[fn] = *(const s16x8*)&P[20480 + boff(fn, ks)];
      }
      __builtin_amdgcn_sched_barrier(0);
      __builtin_amdgcn_s_barrier();
      asm volatile("s_waitcnt lgkmcnt(0)" ::: "memory");
      __builtin_amdgcn_sched_barrier(0);
      __builtin_amdgcn_s_setprio(1);
#pragma unroll
      for (int fm = 0; fm < 2; ++fm)
#pragma unroll
        for (int fn = 0; fn < 2; ++fn) {
          accq[fm][fn] = MFMA32(a_h[fm], b_h[fn], accq[fm][fn]);
          accq[fm][fn] = MFMA32(a_h[fm], b_l[fn], accq[fm][fn]);
          accq[fm][fn] = MFMA32(a_l[fm], b_h[fn], accq[fm][fn]);
        }
      __builtin_amdgcn_s_setprio(0);
      __builtin_amdgcn_sched_barrier(0);
      __builtin_amdgcn_s_barrier();
      // ======== phase K(ks): read Bk, barrier, MFMA cluster ========
#pragma unroll
      for (int fn = 0; fn < 2; ++fn) {
        b_h[fn] = *(const s16x8*)&P[24576 + boff(fn, ks)];
        b_l[fn] = *(const s16x8*)&P[28672 + boff(fn, ks)];
      }
      __builtin_amdgcn_sched_barrier(0);
      __builtin_amdgcn_s_barrier();
      asm volatile("s_waitcnt lgkmcnt(0)" ::: "memory");
      __builtin_amdgcn_sched_barrier(0);
      __builtin_amdgcn_s_setprio(1);
#pragma unroll
      for (int fm = 0; fm < 2; ++fm)
#pragma unroll
        for (int fn = 0; fn < 2; ++fn) {
          acck[fm][fn] = MFMA32(a_h[fm], b_h[fn], acck[fm][fn]);
          acck[fm][fn] = MFMA32(a_h[fm], b_l[fn], acck[fm][fn]);
          acck[fm][fn] = MFMA32(a_l[fm], b_h[fn], acck[fm][fn]);
        }
      __builtin_amdgcn_s_setprio(0);
      __builtin_amdgcn_sched_barrier(0);
      __builtin_amdgcn_s_barrier();
    }
    bp ^= 1;
  }

  // ---- epilogue: RoPE both outputs, shared tables ----
  const int hd = 32 * wn + l31;
#pragma unroll
  for (int fm = 0; fm < 2; ++fm)
#pragma unroll
    for (int r = 0; r < 16; ++r) {
      const int row = bm * 256 + 64 * wm + 32 * fm + (r & 3) + 8 * (r >> 2) + 4 * hi;
      const int s = row & 2047;
      const float cs = cosT[s * 64 + hd], sn = sinT[s * 64 + hd];
      const size_t p1 = (size_t)row * N + bn * 128 + hd;
      {
        const float q1 = accq[fm][0][r], q2 = accq[fm][1][r];
        const float o1 = (q1 * cs - q2 * sn) * qscale;
        const float o2 = (q2 * cs + q1 * sn) * qscale;
        const u16 h1 = f2bf(o1);
        Qh[p1] = h1; Ql[p1] = f2bf(o1 - bf2f(h1));
        const u16 h2 = f2bf(o2);
        Qh[p1 + 64] = h2; Ql[p1 + 64] = f2bf(o2 - bf2f(h2));
      }
      {
        const float k1 = acck[fm][0][r], k2 = acck[fm][1][r];
        const float o1 = k1 * cs - k2 * sn;
        const float o2 = k2 * cs + k1 * sn;
        const u16 h1 = f2bf(o1);
        Kh[p1] = h1; Kl[p1] = f2bf(o1 - bf2f(h1));
        const u16 h2 = f2bf(o2);
        Kh[p1 + 64] = h2; Kl[p1 + 64] = f2bf(o2 - bf2f(h2));
      }
    }
}

// ---------------------------------------------------------------------------
// gemm8:  C(MxN) = A(MxK) * B(NxK)^T, bf16 inputs, fp32 accumulate.
// (1-term uses only now: V^T and Wo projections.)  Unchanged from R10.
// ---------------------------------------------------------------------------
template <int NTERM, int OMODE, int ROPE, int GX>
__global__ __launch_bounds__(512, NTERM == 3 ? 1 : 4)
void gemm8(const u16* __restrict__ Ah, const u16* __restrict__ Al,
           const u16* __restrict__ Bh, const u16* __restrict__ Bl,
           float* __restrict__ Cf, u16* __restrict__ Ch, u16* __restrict__ Cl,
           const float* __restrict__ cosT, const float* __restrict__ sinT,
           float scale, int M, int N, int K) {
  constexpr int BUF = (NTERM == 3) ? 24576 : 12288;   // u16 per buffer
  constexpr int BHI = (NTERM == 3) ? 16384 : 8192;    // B-hi region base
  constexpr int PER = GX / 8;                          // bn per XCD
  constexpr int PSH = (PER == 2) ? 1 : 2;
  static_assert(PER == 2 || PER == 4, "grid.x must be 16 or 32");
  __shared__ u16 SM[3 * BUF];
  const int t = threadIdx.x;
  const int w = t >> 6, lane = t & 63;
  const int l31 = lane & 31, hi = lane >> 5;
  const int wm = w >> 1, wn = w & 1;

  // ---- XCD-locality remap ----
  const int bid = (int)blockIdx.x + GX * (int)blockIdx.y;
  const int xcd = bid & 7, slot = bid >> 3;
  const int bn = PER * xcd + (slot & (PER - 1));
  const int bm = slot >> PSH;

  const size_t arow0 = (size_t)bm * 256, brow0 = (size_t)bn * 128;

  // ---- staging: linear LDS dest, pre-swizzled global source ----
  const int pA0 = 128 * w + lane;          // 16B-chunk index within A region
  const int pA1 = pA0 + 64;
  const int pB0 = 64 * w + lane;
  const int qA0 = pA0 ^ ((pA0 >> 3) & 7);
  const int qA1 = pA1 ^ ((pA1 >> 3) & 7);
  const int qB0 = pB0 ^ ((pB0 >> 3) & 7);
  const size_t gA0 = (arow0 + (qA0 >> 2)) * (size_t)K + (qA0 & 3) * 8;
  const size_t gA1 = (arow0 + (qA1 >> 2)) * (size_t)K + (qA1 & 3) * 8;
  const size_t gB0 = (brow0 + (qB0 >> 2)) * (size_t)K + (qB0 & 3) * 8;

  auto stage = [&](int k0, int bp) {
    u16* P = &SM[bp * BUF];
    gld16(&Ah[gA0 + k0], P + 1024 * w);
    gld16(&Ah[gA1 + k0], P + 1024 * w + 512);
    gld16(&Bh[gB0 + k0], P + BHI + 512 * w);
    if constexpr (NTERM == 3) {
      gld16(&Al[gA0 + k0], P + 8192 + 1024 * w);
      gld16(&Al[gA1 + k0], P + 8192 + 1024 * w + 512);
      gld16(&Bl[gB0 + k0], P + BHI + 4096 + 512 * w);
    }
  };

  // ---- swizzled read offsets (u16 units, within region) ----
  auto aoff = [&](int fm, int ks) {
    int q = ((64 * wm + 32 * fm + l31) << 2) | (2 * ks + hi);
    q ^= (q >> 3) & 7;
    return q * 8;
  };
  auto boff = [&](int fn, int ks) {
    int q = ((32 * wn + 64 * fn + l31) << 2) | (2 * ks + hi);
    q ^= (q >> 3) & 7;
    return q * 8;
  };

  f32x16 acc[2][2];
#pragma unroll
  for (int fm = 0; fm < 2; ++fm)
#pragma unroll
    for (int fn = 0; fn < 2; ++fn)
#pragma unroll
      for (int r = 0; r < 16; ++r) acc[fm][fn][r] = 0.f;

  const int NK = K >> 5;
  stage(0, 0);
  if (NK > 1) stage(32, 1);
  int cur = 0, nxt = 1, fut = 2;
  for (int kt = 0; kt < NK; ++kt) {
    if (kt + 2 < NK) {
      stage((kt + 2) * 32, fut);
      if constexpr (NTERM == 3)
        asm volatile("s_waitcnt vmcnt(12)" ::: "memory");
      else
        asm volatile("s_waitcnt vmcnt(6)" ::: "memory");
    } else if (kt + 1 < NK) {
      if constexpr (NTERM == 3)
        asm volatile("s_waitcnt vmcnt(6)" ::: "memory");
      else
        asm volatile("s_waitcnt vmcnt(3)" ::: "memory");
    } else {
      asm volatile("s_waitcnt vmcnt(0)" ::: "memory");
    }
    __builtin_amdgcn_sched_barrier(0);
    __builtin_amdgcn_s_barrier();
    __builtin_amdgcn_sched_barrier(0);

    const u16* P = &SM[cur * BUF];
    __builtin_amdgcn_s_setprio(1);
#pragma unroll
    for (int ks = 0; ks < 2; ++ks) {
      s16x8 a_h[2], a_l[2], b_h[2], b_l[2];
#pragma unroll
      for (int fm = 0; fm < 2; ++fm) {
        a_h[fm] = *(const s16x8*)&P[aoff(fm, ks)];
        if constexpr (NTERM == 3)
          a_l[fm] = *(const s16x8*)&P[8192 + aoff(fm, ks)];
      }
#pragma unroll
      for (int fn = 0; fn < 2; ++fn) {
        b_h[fn] = *(const s16x8*)&P[BHI + boff(fn, ks)];
        if constexpr (NTERM == 3)
          b_l[fn] = *(const s16x8*)&P[BHI + 4096 + boff(fn, ks)];
      }
#pragma unroll
      for (int fm = 0; fm < 2; ++fm)
#pragma unroll
        for (int fn = 0; fn < 2; ++fn) {
          acc[fm][fn] = MFMA32(a_h[fm], b_h[fn], acc[fm][fn]);
          if constexpr (NTERM == 3) {
            acc[fm][fn] = MFMA32(a_h[fm], b_l[fn], acc[fm][fn]);
            acc[fm][fn] = MFMA32(a_l[fm], b_h[fn], acc[fm][fn]);
          }
        }
    }
    __builtin_amdgcn_s_setprio(0);
    __builtin_amdgcn_s_barrier();
    const int tmp = cur; cur = nxt; nxt = fut; fut = tmp;
  }

  // ---- epilogue ----
  if constexpr (ROPE) {
    // tile is head-aligned (BN=128 = one head). hd in [0,64) pairs with hd+64.
    const int hd = 32 * wn + l31;
#pragma unroll
    for (int fm = 0; fm < 2; ++fm)
#pragma unroll
      for (int r = 0; r < 16; ++r) {
        const int row = bm * 256 + 64 * wm + 32 * fm + (r & 3) + 8 * (r >> 2) + 4 * hi;
        const int s = row & 2047;
        const float cs = cosT[s * 64 + hd], sn = sinT[s * 64 + hd];
        const float q1 = acc[fm][0][r], q2 = acc[fm][1][r];
        const float o1 = (q1 * cs - q2 * sn) * scale;
        const float o2 = (q2 * cs + q1 * sn) * scale;
        const size_t p1 = (size_t)row * N + bn * 128 + hd;
        const u16 h1 = f2bf(o1);
        Ch[p1] = h1; Cl[p1] = f2bf(o1 - bf2f(h1));
        const u16 h2 = f2bf(o2);
        Ch[p1 + 64] = h2; Cl[p1 + 64] = f2bf(o2 - bf2f(h2));
      }
  } else {
#pragma unroll
    for (int fm = 0; fm < 2; ++fm)
#pragma unroll
      for (int fn = 0; fn < 2; ++fn)
#pragma unroll
        for (int r = 0; r < 16; ++r) {
          const int row = bm * 256 + 64 * wm + 32 * fm + (r & 3) + 8 * (r >> 2) + 4 * hi;
          const int col = bn * 128 + 32 * wn + 64 * fn + l31;
          const float v = acc[fm][fn][r];
          if constexpr (OMODE == 0) {
            Cf[(size_t)row * N + col] = v;
          } else if constexpr (OMODE == 1) {
            const u16 hv = f2bf(v);
            Ch[(size_t)row * N + col] = hv;
            Cl[(size_t)row * N + col] = f2bf(v - bf2f(hv));
          } else {
            Ch[(size_t)row * N + col] = f2bf(v);
          }
        }
  }
}

// ---------------------------------------------------------------------------
// Flash attention, causal, 32x32x16 swapped-operand MFMA, counted-vmcnt
// double-buffered pipeline, QBLK=128, k-split wave pairs.  (unchanged R8)
// ---------------------------------------------------------------------------
__global__ __launch_bounds__(512, 2)
void attn(const u16* __restrict__ Qh, const u16* __restrict__ Ql,
          const u16* __restrict__ Kh, const u16* __restrict__ Kl,
          const u16* __restrict__ Vt, u16* __restrict__ Ctx) {
  __shared__ u16 SMEM[65536];               // 128 KB
  // buf p at u16 p*24576: Kh [0,8192) Kl [8192,16384) V [16384,24576)
  // scratch at u16 49152 (32 KB): m/l exchange, then O exchange, then Os

  const int t = threadIdx.x;
  const int w = t >> 6, lane = t & 63;
  const int l31 = lane & 31, hi = lane >> 5;
  const int swz = (l31 & 7) << 3;
  const int j = w >> 1, kh = w & 1;         // q-slice, k-half

  // ---- XCD remap: 16 blocks of a head on one XCD; unique task pairs ----
  const int bid = (int)blockIdx.x + 8 * (int)blockIdx.y + 128 * (int)blockIdx.z;
  const int xcd = bid & 7, slot = bid >> 3;          // slot 0..31
  const int h = xcd * 2 + (slot >> 4);
  const int rem = slot & 15;
  const int qtA = rem & 7, bA = rem >> 3;            // task A: (bA, qtA)
  // task B: (1-bA, 15-qtA).  Coverage: qt<=7 via A, qt>=8 via B, each once.

  // ---- staging source offsets (u16 units), pre-swizzled ----
  const int offK0 = (8 * w + (lane >> 4)) * 2048 + (((lane & 15) ^ ((lane >> 4) & 7)) * 8);
  const int offK1 = (8 * w + 4 + (lane >> 4)) * 2048 + (((lane & 15) ^ ((4 + (lane >> 4)) & 7)) * 8);
  const int offV0 = (16 * w + (lane >> 3)) * 4096 + (((lane & 7) ^ ((lane >> 3) & 7)) * 8);
  const int offV1 = offV0 + 8 * 4096;

  auto stage = [&](const u16* gK, const u16* gKlo, const u16* gV, int kt, int bp) {
    u16* B = &SMEM[bp * 24576];
    const int ka = kt * 131072;   // kt*64*2048
    const int va = kt * 64;
    gld16(gK + ka + offK0, B + 1024 * w);
    gld16(gK + ka + offK1, B + 1024 * w + 512);
    gld16(gKlo + ka + offK0, B + 8192 + 1024 * w);
    gld16(gKlo + ka + offK1, B + 8192 + 1024 * w + 512);
    gld16(gV + va + offV0, B + 16384 + 1024 * w);
    gld16(gV + va + offV1, B + 16384 + 1024 * w + 512);
  };

  int bufph = 0;
  // prime: task A tile 0
  {
    const u16* gK0 = Kh + ((size_t)(bA * 2048)) * 2048 + h * 128;
    const u16* gL0 = Kl + ((size_t)(bA * 2048)) * 2048 + h * 128;
    const u16* gV0 = Vt + (size_t)(h * 128) * 4096 + bA * 2048;
    stage(gK0, gL0, gV0, 0, 0);
  }

  for (int task = 0; task < 2; ++task) {
    const int qt = task ? 15 - qtA : qtA;
    const int bb = task ? 1 - bA : bA;
    const u16* gK0 = Kh + ((size_t)(bb * 2048)) * 2048 + h * 128;
    const u16* gL0 = Kl + ((size_t)(bb * 2048)) * 2048 + h * 128;
    const u16* gV0 = Vt + (size_t)(h * 128) * 4096 + bb * 2048;
    // next task's pointers (for cross-task prefetch)
    const int nb = 1 - bb;
    const u16* nK0 = Kh + ((size_t)(nb * 2048)) * 2048 + h * 128;
    const u16* nL0 = Kl + ((size_t)(nb * 2048)) * 2048 + h * 128;
    const u16* nV0 = Vt + (size_t)(h * 128) * 4096 + nb * 2048;

    const int q0 = qt * 128 + 32 * j;          // wave's first q row
    const int qg = q0 + l31;                   // this lane's q row
    // ---- Q fragments ----
    s16x8 qfh[8], qfl[8];
    {
      const size_t qbase = ((size_t)(bb * 2048 + qg)) * 2048 + h * 128 + 8 * hi;
#pragma unroll
      for (int s = 0; s < 8; ++s) {
        qfh[s] = *(const s16x8*)&Qh[qbase + 16 * s];
        qfl[s] = *(const s16x8*)&Ql[qbase + 16 * s];
      }
    }

    float m_run = -3.0e38f, l_run = 0.f;
    f32x16 o[4];
#pragma unroll
    for (int d = 0; d < 4; ++d)
#pragma unroll
      for (int r = 0; r < 16; ++r) o[d][r] = 0.f;

    const int nt = 2 * qt + 2;
    for (int kt = 0; kt < nt; ++kt) {
      // ---- issue next stage (stays in flight across barriers) ----
      bool staged = true;
      if (kt + 1 < nt)      stage(gK0, gL0, gV0, kt + 1, bufph ^ 1);
      else if (task == 0)   stage(nK0, nL0, nV0, 0, bufph ^ 1);
      else                  staged = false;
      if (staged) asm volatile("s_waitcnt vmcnt(6)" ::: "memory");
      else        asm volatile("s_waitcnt vmcnt(0)" ::: "memory");
      __builtin_amdgcn_sched_barrier(0);
      __builtin_amdgcn_s_barrier();
      __builtin_amdgcn_sched_barrier(0);

      const int kb0 = kt * 64 + 32 * kh;       // wave's k-half base
      const bool active = (q0 + 31) >= kb0;
      if (active) {
        const u16* Kb = &SMEM[bufph * 24576];
        const u16* Lb = Kb + 8192;
        const u16* Vb = Kb + 16384;
        // ---- S^T (wave's 32k x 32q block), split precision 3-term ----
        f32x16 acc;
#pragma unroll
        for (int r = 0; r < 16; ++r) acc[r] = 0.f;
        __builtin_amdgcn_s_setprio(1);
#pragma unroll
        for (int s = 0; s < 8; ++s) {
          const int col = 16 * s + 8 * hi;
          const s16x8 kha = *(const s16x8*)&Kb[((32 * kh + l31) * 128 + col) ^ swz];
          const s16x8 kla = *(const s16x8*)&Lb[((32 * kh + l31) * 128 + col) ^ swz];
          acc = MFMA32(kha, qfh[s], acc);
          acc = MFMA32(kla, qfh[s], acc);
          acc = MFMA32(kha, qfl[s], acc);
        }
        __builtin_amdgcn_s_setprio(0);

        // ---- causal mask + online softmax (lane-local, wave-private) ----
        const bool partial = (kb0 + 31) > q0;
        float mx = -3.0e38f;
#pragma unroll
        for (int r = 0; r < 16; ++r) {
          const int koff = (r & 3) + 8 * (r >> 2) + 4 * hi;
          float v = acc[r];
          if (partial && (kb0 + koff > qg)) v = -3.0e38f;
          acc[r] = v;
          mx = fmaxf(mx, v);
        }
        mx = fmaxf(mx, __shfl_xor(mx, 32));    // combine hi halves (same q)
        const float mn = fmaxf(m_run, mx);
        const float al = __expf(m_run - mn);
        m_run = mn;
        float rs = 0.f;
#pragma unroll
        for (int r = 0; r < 16; ++r) {
          const float e = __expf(acc[r] - mn);
          acc[r] = e;
          rs += e;
        }
        rs += __shfl_xor(rs, 32);
        l_run = l_run * al + rs;
#pragma unroll
        for (int d = 0; d < 4; ++d)
#pragma unroll
          for (int r = 0; r < 16; ++r) o[d][r] *= al;

        // ---- pack P -> PV B-fragments (cvt_pk + permlane32_swap) ----
        s16x8 pb[2];
#pragma unroll
        for (int tt = 0; tt < 2; ++tt) {
          const int q2A = 2 * tt;
          const float e0 = acc[4 * q2A + 0], e1 = acc[4 * q2A + 1];
          const float e2 = acc[4 * q2A + 2], e3 = acc[4 * q2A + 3];
          const float f0 = acc[4 * q2A + 4], f1 = acc[4 * q2A + 5];
          const float f2 = acc[4 * q2A + 6], f3 = acc[4 * q2A + 7];
          unsigned a0 = cvtpk_bf16(e0, e1);
          unsigned a1 = cvtpk_bf16(e2, e3);
          unsigned b0 = cvtpk_bf16(f0, f1);
          unsigned b1 = cvtpk_bf16(f2, f3);
          asm volatile("v_permlane32_swap_b32 %0, %1" : "+v"(a0), "+v"(b0));
          asm volatile("v_permlane32_swap_b32 %0, %1" : "+v"(a1), "+v"(b1));
          union { unsigned u[4]; s16x8 v; } pk;
          pk.u[0] = a0; pk.u[1] = a1; pk.u[2] = b0; pk.u[3] = b1;
          pb[tt] = pk.v;
        }

        // ---- O^T += V^T[:, wave's k-half] * P ----
        __builtin_amdgcn_s_setprio(1);
#pragma unroll
        for (int d = 0; d < 4; ++d) {
#pragma unroll
          for (int tt = 0; tt < 2; ++tt) {
            const s16x8 va = *(const s16x8*)
                &Vb[((32 * d + l31) * 64 + 16 * (2 * kh + tt) + 8 * hi) ^ swz];
            o[d] = MFMA32(va, pb[tt], o[d]);
          }
        }
        __builtin_amdgcn_s_setprio(0);
      }
      __builtin_amdgcn_s_barrier();
      bufph ^= 1;
    }

    // ======== epilogue: merge k-half wave pairs, normalize, store ========
    float* Sf = (float*)&SMEM[49152];          // 32KB scratch as f32[8192]
    // (1) m/l exchange
    Sf[w * 64 + lane] = m_run;
    Sf[512 + w * 64 + lane] = l_run;
    asm volatile("s_waitcnt lgkmcnt(0)" ::: "memory");
    __builtin_amdgcn_s_barrier();
    const float mOth = Sf[(w ^ 1) * 64 + lane];
    const float lOth = Sf[512 + (w ^ 1) * 64 + lane];
    const float mC = fmaxf(m_run, mOth);
    const float eS = __expf(m_run - mC);
    const float eO = __expf(mOth - mC);
    const float lC = eS * l_run + eO * lOth;
    // scale own partial O (odd waves hand over pre-scaled)
#pragma unroll
    for (int d = 0; d < 4; ++d)
#pragma unroll
      for (int r = 0; r < 16; ++r) o[d][r] *= eS;
    __builtin_amdgcn_s_barrier();              // m/l reads done before reuse
    // (2) O exchange: odd wave -> even wave, 2 rounds of 32KB
#pragma unroll
    for (int round = 0; round < 2; ++round) {
      if ((w >> 2) == round && kh == 1) {
        const int sl = j & 1;
#pragma unroll
        for (int d = 0; d < 4; ++d)
#pragma unroll
          for (int rr = 0; rr < 4; ++rr) {
            float4v c;
            c[0] = o[d][4 * rr + 0]; c[1] = o[d][4 * rr + 1];
            c[2] = o[d][4 * rr + 2]; c[3] = o[d][4 * rr + 3];
            const int cidx = 4 * (d * 4 + rr);
            *(float4v*)&Sf[sl * 4096 + ((lane * 64 + cidx) ^ ((lane & 7) << 2))] = c;
          }
      }
      asm volatile("s_waitcnt lgkmcnt(0)" ::: "memory");
      __builtin_amdgcn_s_barrier();
      if ((w >> 2) == round && kh == 0) {
        const int sl = j & 1;
#pragma unroll
        for (int d = 0; d < 4; ++d)
#pragma unroll
          for (int rr = 0; rr < 4; ++rr) {
            const int cidx = 4 * (d * 4 + rr);
            const float4v c =
                *(const float4v*)&Sf[sl * 4096 + ((lane * 64 + cidx) ^ ((lane & 7) << 2))];
            o[d][4 * rr + 0] += c[0]; o[d][4 * rr + 1] += c[1];
            o[d][4 * rr + 2] += c[2]; o[d][4 * rr + 3] += c[3];
          }
      }
      __builtin_amdgcn_s_barrier();
    }
    // (3) even waves: normalize + transposed bf16 write to Os
    u16* Os = &SMEM[49152];                    // [128][128] u16, swizzled
    if (kh == 0) {
      const float inv_l = 1.0f / lC;
      const int rl = 32 * j + l31;
#pragma unroll
      for (int d = 0; d < 4; ++d)
#pragma unroll
        for (int r = 0; r < 16; r += 2) {
          const int dd = 32 * d + (r & 3) + 8 * (r >> 2) + 4 * hi;
          const unsigned pr = cvtpk_bf16(o[d][r] * inv_l, o[d][r + 1] * inv_l);
          *(unsigned*)&Os[(rl * 128 + dd) ^ ((rl & 7) << 3)] = pr;
        }
    }
    asm volatile("s_waitcnt lgkmcnt(0)" ::: "memory");
    __builtin_amdgcn_s_barrier();
    // (4) coalesced store, all 8 waves
    {
      const int rr = t >> 2, cb = (t & 3) * 32;
      const size_t ob =
          ((size_t)(bb * 2048 + qt * 128 + rr)) * 2048 + h * 128 + cb;
#pragma unroll
      for (int p = 0; p < 4; ++p)
        *(u16x8*)&Ctx[ob + 8 * p] =
            *(const u16x8*)&Os[(rr * 128 + cb + 8 * p) ^ ((rr & 7) << 3)];
    }
    asm volatile("s_waitcnt lgkmcnt(0)" ::: "memory");
    __builtin_amdgcn_s_barrier();
  }
}

// ---------------------------------------------------------------------------
extern "C" void kernel_launch(void* const* d_in, const int* in_sizes, int n_in,
                              void* d_out, int out_size, void* d_ws, size_t ws_size,
                              hipStream_t stream) {
  const float* x  = (const float*)d_in[0];
  const float* Wq = (const float*)d_in[1];
  const float* Wk = (const float*)d_in[2];
  const float* Wv = (const float*)d_in[3];
  const float* Wo = (const float*)d_in[4];
  float* out = (float*)d_out;

  char* ws = (char*)d_ws;
  size_t off = 0;
  auto alloc = [&](size_t bytes) {
    char* p = ws + off;
    off += (bytes + 255) & ~(size_t)255;
    return p;
  };
  const size_t XE = (size_t)4096 * 2048;   // B*S x H elements
  const size_t WE = (size_t)2048 * 2048;

  u16* xh  = (u16*)alloc(XE * 2);
  u16* xl  = (u16*)alloc(XE * 2);
  u16* Wqh = (u16*)alloc(WE * 2);
  u16* Wql = (u16*)alloc(WE * 2);
  u16* Wkh = (u16*)alloc(WE * 2);
  u16* Wkl = (u16*)alloc(WE * 2);
  u16* Wvh = (u16*)alloc(WE * 2);
  u16* Woh = (u16*)alloc(WE * 2);
  u16* Qhb = (u16*)alloc(XE * 2);
  u16* Qlb = (u16*)alloc(XE * 2);
  u16* Khb = (u16*)alloc(XE * 2);
  u16* Klb = (u16*)alloc(XE * 2);
  u16* Vtb = (u16*)alloc(XE * 2);   // V^T: [2048 dims][4096 seq]
  u16* Ctxb = (u16*)alloc(XE * 2);
  float* cosT = (float*)alloc((size_t)2048 * 64 * 4);
  float* sinT = (float*)alloc((size_t)2048 * 64 * 4);
  (void)ws_size;  // requires ~170 MB of workspace
  (void)in_sizes; (void)n_in; (void)out_size;

  // 1) precision split + RoPE tables
  split_bf16<<<8192, 256, 0, stream>>>(x, xh, xl, (int)(XE / 4));
  split_bf16<<<4096, 256, 0, stream>>>(Wq, Wqh, Wql, (int)(WE / 4));
  split_bf16<<<4096, 256, 0, stream>>>(Wk, Wkh, Wkl, (int)(WE / 4));
  split_bf16<<<4096, 256, 0, stream>>>(Wv, Wvh, nullptr, (int)(WE / 4));
  split_bf16<<<4096, 256, 0, stream>>>(Wo, Woh, nullptr, (int)(WE / 4));
  rope_tab<<<512, 256, 0, stream>>>(cosT, sinT);

  // 2) fused Q+K projection (shared A staging, shared RoPE tables)
  gemm_qk<<<dim3(16, 16), 512, 0, stream>>>(
      xh, xl, Wqh, Wql, Wkh, Wkl, Qhb, Qlb, Khb, Klb, cosT, sinT,
      11.313708498984760f, 4096, 2048, 2048);
  // V^T = Wv * x^T :  A=Wv (M=2048 dims), B=x (N=4096 seq)
  gemm8<1, 2, 0, 32><<<dim3(32, 8), 512, 0, stream>>>(
      Wvh, nullptr, xh, nullptr, nullptr, Vtb, nullptr, nullptr, nullptr,
      1.0f, 2048, 4096, 2048);

  // 3) causal flash attention (de-duped task map, k-split wave pairs)
  attn<<<dim3(8, 16, 2), 512, 0, stream>>>(Qhb, Qlb, Khb, Klb, Vtb, Ctxb);

  // 4) output projection -> fp32 d_out
  gemm8<1, 0, 0, 16><<<dim3(16, 16), 512, 0, stream>>>(
      Ctxb, nullptr, Woh, nullptr, out, nullptr, nullptr, nullptr, nullptr,
      1.0f, 4096, 2048, 2048);
}

// Round 9
// 519.806 us; speedup vs baseline: 1.0175x; 1.0175x over previous
//
#include <hip/hip_runtime.h>
#include <cmath>

// ============================================================================
// AutoregressiveGroupQuerySelfAttention  (B=2, S=2048, H=2048, nH=16, D=128)
//
// Round 13: correct m201-style fine-interleaved phase port of gemm_qk.
// R12's coarse split (bulk staging + 8 barriers/step) hit m196's documented
// -20% failure mode. This version:
//  - 2 phases per BK=32 step: A={read a+bq, issue A-gloads(t+1), barrier,
//    lgkm0, 24 Q-MFMAs, barrier}, B={read bk, issue B-gloads(t+1), barrier,
//    lgkm0, 24 K-MFMAs, vmcnt(0), barrier}. 4 barriers/step = m201 density.
//  - Staging spread: A-loads (HBM/L3, long cover) issued in phase A;
//    B-loads (L2-resident via XCD remap) in phase B. Tile validity = the
//    vmcnt(0) after phase-B MFMA + closing barrier (full-step cover for A).
//  - a-frags held across A->B; VGPR ~220 -> launch_bounds(512,1) (LDS
//    already caps at 1 block/CU; (512,2)'s 128-VGPR cap would spill).
//  - Per-accumulator MFMA order unchanged -> bitwise-identical results.
//  - gemm8 (1-term), attn, aux kernels unchanged.
// ============================================================================

typedef unsigned short u16;
typedef __attribute__((ext_vector_type(4))) float  f32x4;
typedef __attribute__((ext_vector_type(16))) float f32x16;
typedef __attribute__((ext_vector_type(4))) float  float4v;
typedef __attribute__((ext_vector_type(4))) unsigned short u16x4;
typedef __attribute__((ext_vector_type(8))) unsigned short u16x8;
typedef __attribute__((ext_vector_type(8))) short s16x8;

__device__ __forceinline__ u16 f2bf(float f) {
  unsigned u = __float_as_uint(f);
  u += 0x7FFFu + ((u >> 16) & 1u);            // RNE; inputs are finite
  return (u16)(u >> 16);
}
__device__ __forceinline__ float bf2f(u16 h) {
  return __uint_as_float(((unsigned)h) << 16);
}
__device__ __forceinline__ f32x16 MFMA32(s16x8 a, s16x8 b, f32x16 c) {
  return __builtin_amdgcn_mfma_f32_32x32x16_bf16(a, b, c, 0, 0, 0);
}
__device__ __forceinline__ unsigned cvtpk_bf16(float lo, float hi) {
  unsigned r;
  asm("v_cvt_pk_bf16_f32 %0, %1, %2" : "=v"(r) : "v"(lo), "v"(hi));
  return r;
}
// async global->LDS, 16B per lane; LDS dest = wave-uniform base + lane*16
__device__ __forceinline__ void gld16(const void* g, void* s) {
  __builtin_amdgcn_global_load_lds(
      (const __attribute__((address_space(1))) void*)g,
      (__attribute__((address_space(3))) void*)s, 16, 0, 0);
}

// ---------------------------------------------------------------------------
// fp32 -> bf16 hi (+ optional lo residual).  n4 = element count / 4.
// ---------------------------------------------------------------------------
__global__ void split_bf16(const float* __restrict__ src, u16* __restrict__ hi,
                           u16* __restrict__ lo, int n4) {
  int i = blockIdx.x * 256 + threadIdx.x;
  if (i >= n4) return;
  float4v v = ((const float4v*)src)[i];
  u16x4 hv, lv;
#pragma unroll
  for (int j = 0; j < 4; ++j) {
    float f = v[j];
    u16 h = f2bf(f);
    hv[j] = h;
    lv[j] = f2bf(f - bf2f(h));
  }
  ((u16x4*)hi)[i] = hv;
  if (lo) ((u16x4*)lo)[i] = lv;
}

// ---------------------------------------------------------------------------
// RoPE tables in fp64.
// ---------------------------------------------------------------------------
__global__ void rope_tab(float* __restrict__ cosT, float* __restrict__ sinT) {
  int idx = blockIdx.x * 256 + threadIdx.x;   // 2048*64
  int i = idx & 63, s = idx >> 6;
  double invf = pow(10000.0, -(double)i / 64.0);
  double ang = (double)s * invf;
  cosT[idx] = (float)cos(ang);
  sinT[idx] = (float)sin(ang);
}

// ---------------------------------------------------------------------------
// gemm_qk: fused Q/K projection.  Q = x Wq^T (RoPE, *qscale), K = x Wk^T
// (RoPE). Split-precision 3-term on both. 256x128 tile, BK=32, 512 thr =
// 8 waves (wm=w>>1, wn=w&1), per-wave 64x64 per output.
// LDS buffer (u16): A_hi[0,8192) A_lo[8192,16384) Bq_hi[16384,20480)
// Bq_lo[20480,24576) Bk_hi[24576,28672) Bk_lo[28672,32768). 2 bufs = 128KB.
// K-loop: 2 fine-interleaved phases/step (see header). 16B-chunk involution
// swizzle (pre-swizzled global source + swizzled ds_read); XCD remap.
// ---------------------------------------------------------------------------
__global__ __launch_bounds__(512, 1)
void gemm_qk(const u16* __restrict__ xh, const u16* __restrict__ xl,
             const u16* __restrict__ Wqh, const u16* __restrict__ Wql,
             const u16* __restrict__ Wkh, const u16* __restrict__ Wkl,
             u16* __restrict__ Qh, u16* __restrict__ Ql,
             u16* __restrict__ Kh, u16* __restrict__ Kl,
             const float* __restrict__ cosT, const float* __restrict__ sinT,
             float qscale, int M, int N, int K) {
  __shared__ u16 SM[2 * 32768];                 // 128 KB
  const int t = threadIdx.x;
  const int w = t >> 6, lane = t & 63;
  const int l31 = lane & 31, hi = lane >> 5;
  const int wm = w >> 1, wn = w & 1;

  // ---- XCD-locality remap (grid.x = 16 -> 2 bn per XCD) ----
  const int bid = (int)blockIdx.x + 16 * (int)blockIdx.y;
  const int xcd = bid & 7, slot = bid >> 3;
  const int bn = 2 * xcd + (slot & 1);
  const int bm = slot >> 1;

  const size_t arow0 = (size_t)bm * 256, brow0 = (size_t)bn * 128;

  // ---- staging: linear LDS dest, pre-swizzled global source ----
  const int pA0 = 128 * w + lane;          // 16B-chunk index within A region
  const int pA1 = pA0 + 64;
  const int pB0 = 64 * w + lane;
  const int qA0 = pA0 ^ ((pA0 >> 3) & 7);
  const int qA1 = pA1 ^ ((pA1 >> 3) & 7);
  const int qB0 = pB0 ^ ((pB0 >> 3) & 7);
  const size_t gA0 = (arow0 + (qA0 >> 2)) * (size_t)K + (qA0 & 3) * 8;
  const size_t gA1 = (arow0 + (qA1 >> 2)) * (size_t)K + (qA1 & 3) * 8;
  const size_t gB0 = (brow0 + (qB0 >> 2)) * (size_t)K + (qB0 & 3) * 8;

  auto stageA = [&](int k0, int bp) {        // A (x) hi+lo : 4 loads
    u16* P = &SM[bp * 32768];
    gld16(&xh[gA0 + k0], P + 1024 * w);
    gld16(&xh[gA1 + k0], P + 1024 * w + 512);
    gld16(&xl[gA0 + k0], P + 8192 + 1024 * w);
    gld16(&xl[gA1 + k0], P + 8192 + 1024 * w + 512);
  };
  auto stageB = [&](int k0, int bp) {        // B (Wq,Wk) hi+lo : 4 loads
    u16* P = &SM[bp * 32768];
    gld16(&Wqh[gB0 + k0], P + 16384 + 512 * w);
    gld16(&Wql[gB0 + k0], P + 20480 + 512 * w);
    gld16(&Wkh[gB0 + k0], P + 24576 + 512 * w);
    gld16(&Wkl[gB0 + k0], P + 28672 + 512 * w);
  };

  // ---- swizzled read offsets (u16 units, within region) ----
  auto aoff = [&](int fm, int ks) {
    int q = ((64 * wm + 32 * fm + l31) << 2) | (2 * ks + hi);
    q ^= (q >> 3) & 7;
    return q * 8;
  };
  auto boff = [&](int fn, int ks) {
    int q = ((32 * wn + 64 * fn + l31) << 2) | (2 * ks + hi);
    q ^= (q >> 3) & 7;
    return q * 8;
  };

  f32x16 accq[2][2], acck[2][2];
#pragma unroll
  for (int fm = 0; fm < 2; ++fm)
#pragma unroll
    for (int fn = 0; fn < 2; ++fn)
#pragma unroll
      for (int r = 0; r < 16; ++r) { accq[fm][fn][r] = 0.f; acck[fm][fn][r] = 0.f; }

  const int NK = K >> 5;
  // ---- prologue: tile 0 fully staged, validated ----
  stageA(0, 0);
  stageB(0, 0);
  asm volatile("s_waitcnt vmcnt(0)" ::: "memory");
  __builtin_amdgcn_sched_barrier(0);
  __builtin_amdgcn_s_barrier();
  __builtin_amdgcn_sched_barrier(0);

  int bp = 0;
  for (int kt = 0; kt < NK; ++kt) {
    const u16* P = &SM[bp * 32768];
    const bool more = (kt + 1 < NK);

    // ======== phase A: reads a+bq, issue A-gloads, 24 Q-MFMAs ========
    s16x8 a_h[2][2], a_l[2][2];
    {
      s16x8 bq_h[2][2], bq_l[2][2];
#pragma unroll
      for (int ks = 0; ks < 2; ++ks)
#pragma unroll
        for (int fm = 0; fm < 2; ++fm) {
          a_h[ks][fm] = *(const s16x8*)&P[aoff(fm, ks)];
          a_l[ks][fm] = *(const s16x8*)&P[8192 + aoff(fm, ks)];
        }
#pragma unroll
      for (int ks = 0; ks < 2; ++ks)
#pragma unroll
        for (int fn = 0; fn < 2; ++fn) {
          bq_h[ks][fn] = *(const s16x8*)&P[16384 + boff(fn, ks)];
          bq_l[ks][fn] = *(const s16x8*)&P[20480 + boff(fn, ks)];
        }
      if (more) stageA((kt + 1) * 32, bp ^ 1);
      __builtin_amdgcn_sched_barrier(0);
      __builtin_amdgcn_s_barrier();
      asm volatile("s_waitcnt lgkmcnt(0)" ::: "memory");
      __builtin_amdgcn_sched_barrier(0);
      __builtin_amdgcn_s_setprio(1);
#pragma unroll
      for (int ks = 0; ks < 2; ++ks)
#pragma unroll
        for (int fm = 0; fm < 2; ++fm)
#pragma unroll
          for (int fn = 0; fn < 2; ++fn) {
            accq[fm][fn] = MFMA32(a_h[ks][fm], bq_h[ks][fn], accq[fm][fn]);
            accq[fm][fn] = MFMA32(a_h[ks][fm], bq_l[ks][fn], accq[fm][fn]);
            accq[fm][fn] = MFMA32(a_l[ks][fm], bq_h[ks][fn], accq[fm][fn]);
          }
      __builtin_amdgcn_s_setprio(0);
      __builtin_amdgcn_sched_barrier(0);
      __builtin_amdgcn_s_barrier();
      __builtin_amdgcn_sched_barrier(0);
    }

    // ======== phase B: reads bk, issue B-gloads, 24 K-MFMAs ========
    {
      s16x8 bk_h[2][2], bk_l[2][2];
#pragma unroll
      for (int ks = 0; ks < 2; ++ks)
#pragma unroll
        for (int fn = 0; fn < 2; ++fn) {
          bk_h[ks][fn] = *(const s16x8*)&P[24576 + boff(fn, ks)];
          bk_l[ks][fn] = *(const s16x8*)&P[28672 + boff(fn, ks)];
        }
      if (more) stageB((kt + 1) * 32, bp ^ 1);
      __builtin_amdgcn_sched_barrier(0);
      __builtin_amdgcn_s_barrier();
      asm volatile("s_waitcnt lgkmcnt(0)" ::: "memory");
      __builtin_amdgcn_sched_barrier(0);
      __builtin_amdgcn_s_setprio(1);
#pragma unroll
      for (int ks = 0; ks < 2; ++ks)
#pragma unroll
        for (int fm = 0; fm < 2; ++fm)
#pragma unroll
          for (int fn = 0; fn < 2; ++fn) {
            acck[fm][fn] = MFMA32(a_h[ks][fm], bk_h[ks][fn], acck[fm][fn]);
            acck[fm][fn] = MFMA32(a_h[ks][fm], bk_l[ks][fn], acck[fm][fn]);
            acck[fm][fn] = MFMA32(a_l[ks][fm], bk_h[ks][fn], acck[fm][fn]);
          }
      __builtin_amdgcn_s_setprio(0);
      __builtin_amdgcn_sched_barrier(0);
      // tile t+1 validity boundary: drain its loads (issued this step;
      // A-loads got ~a full step of cover), then closing barrier.
      asm volatile("s_waitcnt vmcnt(0)" ::: "memory");
      __builtin_amdgcn_s_barrier();
      __builtin_amdgcn_sched_barrier(0);
    }
    bp ^= 1;
  }

  // ---- epilogue: RoPE both outputs, shared tables ----
  const int hd = 32 * wn + l31;
#pragma unroll
  for (int fm = 0; fm < 2; ++fm)
#pragma unroll
    for (int r = 0; r < 16; ++r) {
      const int row = bm * 256 + 64 * wm + 32 * fm + (r & 3) + 8 * (r >> 2) + 4 * hi;
      const int s = row & 2047;
      const float cs = cosT[s * 64 + hd], sn = sinT[s * 64 + hd];
      const size_t p1 = (size_t)row * N + bn * 128 + hd;
      {
        const float q1 = accq[fm][0][r], q2 = accq[fm][1][r];
        const float o1 = (q1 * cs - q2 * sn) * qscale;
        const float o2 = (q2 * cs + q1 * sn) * qscale;
        const u16 h1 = f2bf(o1);
        Qh[p1] = h1; Ql[p1] = f2bf(o1 - bf2f(h1));
        const u16 h2 = f2bf(o2);
        Qh[p1 + 64] = h2; Ql[p1 + 64] = f2bf(o2 - bf2f(h2));
      }
      {
        const float k1 = acck[fm][0][r], k2 = acck[fm][1][r];
        const float o1 = k1 * cs - k2 * sn;
        const float o2 = k2 * cs + k1 * sn;
        const u16 h1 = f2bf(o1);
        Kh[p1] = h1; Kl[p1] = f2bf(o1 - bf2f(h1));
        const u16 h2 = f2bf(o2);
        Kh[p1 + 64] = h2; Kl[p1 + 64] = f2bf(o2 - bf2f(h2));
      }
    }
}

// ---------------------------------------------------------------------------
// gemm8:  C(MxN) = A(MxK) * B(NxK)^T, bf16 inputs, fp32 accumulate.
// (1-term uses only now: V^T and Wo projections.)  Unchanged from R10.
// ---------------------------------------------------------------------------
template <int NTERM, int OMODE, int ROPE, int GX>
__global__ __launch_bounds__(512, NTERM == 3 ? 1 : 4)
void gemm8(const u16* __restrict__ Ah, const u16* __restrict__ Al,
           const u16* __restrict__ Bh, const u16* __restrict__ Bl,
           float* __restrict__ Cf, u16* __restrict__ Ch, u16* __restrict__ Cl,
           const float* __restrict__ cosT, const float* __restrict__ sinT,
           float scale, int M, int N, int K) {
  constexpr int BUF = (NTERM == 3) ? 24576 : 12288;   // u16 per buffer
  constexpr int BHI = (NTERM == 3) ? 16384 : 8192;    // B-hi region base
  constexpr int PER = GX / 8;                          // bn per XCD
  constexpr int PSH = (PER == 2) ? 1 : 2;
  static_assert(PER == 2 || PER == 4, "grid.x must be 16 or 32");
  __shared__ u16 SM[3 * BUF];
  const int t = threadIdx.x;
  const int w = t >> 6, lane = t & 63;
  const int l31 = lane & 31, hi = lane >> 5;
  const int wm = w >> 1, wn = w & 1;

  // ---- XCD-locality remap ----
  const int bid = (int)blockIdx.x + GX * (int)blockIdx.y;
  const int xcd = bid & 7, slot = bid >> 3;
  const int bn = PER * xcd + (slot & (PER - 1));
  const int bm = slot >> PSH;

  const size_t arow0 = (size_t)bm * 256, brow0 = (size_t)bn * 128;

  // ---- staging: linear LDS dest, pre-swizzled global source ----
  const int pA0 = 128 * w + lane;          // 16B-chunk index within A region
  const int pA1 = pA0 + 64;
  const int pB0 = 64 * w + lane;
  const int qA0 = pA0 ^ ((pA0 >> 3) & 7);
  const int qA1 = pA1 ^ ((pA1 >> 3) & 7);
  const int qB0 = pB0 ^ ((pB0 >> 3) & 7);
  const size_t gA0 = (arow0 + (qA0 >> 2)) * (size_t)K + (qA0 & 3) * 8;
  const size_t gA1 = (arow0 + (qA1 >> 2)) * (size_t)K + (qA1 & 3) * 8;
  const size_t gB0 = (brow0 + (qB0 >> 2)) * (size_t)K + (qB0 & 3) * 8;

  auto stage = [&](int k0, int bp) {
    u16* P = &SM[bp * BUF];
    gld16(&Ah[gA0 + k0], P + 1024 * w);
    gld16(&Ah[gA1 + k0], P + 1024 * w + 512);
    gld16(&Bh[gB0 + k0], P + BHI + 512 * w);
    if constexpr (NTERM == 3) {
      gld16(&Al[gA0 + k0], P + 8192 + 1024 * w);
      gld16(&Al[gA1 + k0], P + 8192 + 1024 * w + 512);
      gld16(&Bl[gB0 + k0], P + BHI + 4096 + 512 * w);
    }
  };

  // ---- swizzled read offsets (u16 units, within region) ----
  auto aoff = [&](int fm, int ks) {
    int q = ((64 * wm + 32 * fm + l31) << 2) | (2 * ks + hi);
    q ^= (q >> 3) & 7;
    return q * 8;
  };
  auto boff = [&](int fn, int ks) {
    int q = ((32 * wn + 64 * fn + l31) << 2) | (2 * ks + hi);
    q ^= (q >> 3) & 7;
    return q * 8;
  };

  f32x16 acc[2][2];
#pragma unroll
  for (int fm = 0; fm < 2; ++fm)
#pragma unroll
    for (int fn = 0; fn < 2; ++fn)
#pragma unroll
      for (int r = 0; r < 16; ++r) acc[fm][fn][r] = 0.f;

  const int NK = K >> 5;
  stage(0, 0);
  if (NK > 1) stage(32, 1);
  int cur = 0, nxt = 1, fut = 2;
  for (int kt = 0; kt < NK; ++kt) {
    if (kt + 2 < NK) {
      stage((kt + 2) * 32, fut);
      if constexpr (NTERM == 3)
        asm volatile("s_waitcnt vmcnt(12)" ::: "memory");
      else
        asm volatile("s_waitcnt vmcnt(6)" ::: "memory");
    } else if (kt + 1 < NK) {
      if constexpr (NTERM == 3)
        asm volatile("s_waitcnt vmcnt(6)" ::: "memory");
      else
        asm volatile("s_waitcnt vmcnt(3)" ::: "memory");
    } else {
      asm volatile("s_waitcnt vmcnt(0)" ::: "memory");
    }
    __builtin_amdgcn_sched_barrier(0);
    __builtin_amdgcn_s_barrier();
    __builtin_amdgcn_sched_barrier(0);

    const u16* P = &SM[cur * BUF];
    __builtin_amdgcn_s_setprio(1);
#pragma unroll
    for (int ks = 0; ks < 2; ++ks) {
      s16x8 a_h[2], a_l[2], b_h[2], b_l[2];
#pragma unroll
      for (int fm = 0; fm < 2; ++fm) {
        a_h[fm] = *(const s16x8*)&P[aoff(fm, ks)];
        if constexpr (NTERM == 3)
          a_l[fm] = *(const s16x8*)&P[8192 + aoff(fm, ks)];
      }
#pragma unroll
      for (int fn = 0; fn < 2; ++fn) {
        b_h[fn] = *(const s16x8*)&P[BHI + boff(fn, ks)];
        if constexpr (NTERM == 3)
          b_l[fn] = *(const s16x8*)&P[BHI + 4096 + boff(fn, ks)];
      }
#pragma unroll
      for (int fm = 0; fm < 2; ++fm)
#pragma unroll
        for (int fn = 0; fn < 2; ++fn) {
          acc[fm][fn] = MFMA32(a_h[fm], b_h[fn], acc[fm][fn]);
          if constexpr (NTERM == 3) {
            acc[fm][fn] = MFMA32(a_h[fm], b_l[fn], acc[fm][fn]);
            acc[fm][fn] = MFMA32(a_l[fm], b_h[fn], acc[fm][fn]);
          }
        }
    }
    __builtin_amdgcn_s_setprio(0);
    __builtin_amdgcn_s_barrier();
    const int tmp = cur; cur = nxt; nxt = fut; fut = tmp;
  }

  // ---- epilogue ----
  if constexpr (ROPE) {
    // tile is head-aligned (BN=128 = one head). hd in [0,64) pairs with hd+64.
    const int hd = 32 * wn + l31;
#pragma unroll
    for (int fm = 0; fm < 2; ++fm)
#pragma unroll
      for (int r = 0; r < 16; ++r) {
        const int row = bm * 256 + 64 * wm + 32 * fm + (r & 3) + 8 * (r >> 2) + 4 * hi;
        const int s = row & 2047;
        const float cs = cosT[s * 64 + hd], sn = sinT[s * 64 + hd];
        const float q1 = acc[fm][0][r], q2 = acc[fm][1][r];
        const float o1 = (q1 * cs - q2 * sn) * scale;
        const float o2 = (q2 * cs + q1 * sn) * scale;
        const size_t p1 = (size_t)row * N + bn * 128 + hd;
        const u16 h1 = f2bf(o1);
        Ch[p1] = h1; Cl[p1] = f2bf(o1 - bf2f(h1));
        const u16 h2 = f2bf(o2);
        Ch[p1 + 64] = h2; Cl[p1 + 64] = f2bf(o2 - bf2f(h2));
      }
  } else {
#pragma unroll
    for (int fm = 0; fm < 2; ++fm)
#pragma unroll
      for (int fn = 0; fn < 2; ++fn)
#pragma unroll
        for (int r = 0; r < 16; ++r) {
          const int row = bm * 256 + 64 * wm + 32 * fm + (r & 3) + 8 * (r >> 2) + 4 * hi;
          const int col = bn * 128 + 32 * wn + 64 * fn + l31;
          const float v = acc[fm][fn][r];
          if constexpr (OMODE == 0) {
            Cf[(size_t)row * N + col] = v;
          } else if constexpr (OMODE == 1) {
            const u16 hv = f2bf(v);
            Ch[(size_t)row * N + col] = hv;
            Cl[(size_t)row * N + col] = f2bf(v - bf2f(hv));
          } else {
            Ch[(size_t)row * N + col] = f2bf(v);
          }
        }
  }
}

// ---------------------------------------------------------------------------
// Flash attention, causal, 32x32x16 swapped-operand MFMA, counted-vmcnt
// double-buffered pipeline, QBLK=128, k-split wave pairs.  (unchanged R8)
// ---------------------------------------------------------------------------
__global__ __launch_bounds__(512, 2)
void attn(const u16* __restrict__ Qh, const u16* __restrict__ Ql,
          const u16* __restrict__ Kh, const u16* __restrict__ Kl,
          const u16* __restrict__ Vt, u16* __restrict__ Ctx) {
  __shared__ u16 SMEM[65536];               // 128 KB
  // buf p at u16 p*24576: Kh [0,8192) Kl [8192,16384) V [16384,24576)
  // scratch at u16 49152 (32 KB): m/l exchange, then O exchange, then Os

  const int t = threadIdx.x;
  const int w = t >> 6, lane = t & 63;
  const int l31 = lane & 31, hi = lane >> 5;
  const int swz = (l31 & 7) << 3;
  const int j = w >> 1, kh = w & 1;         // q-slice, k-half

  // ---- XCD remap: 16 blocks of a head on one XCD; unique task pairs ----
  const int bid = (int)blockIdx.x + 8 * (int)blockIdx.y + 128 * (int)blockIdx.z;
  const int xcd = bid & 7, slot = bid >> 3;          // slot 0..31
  const int h = xcd * 2 + (slot >> 4);
  const int rem = slot & 15;
  const int qtA = rem & 7, bA = rem >> 3;            // task A: (bA, qtA)
  // task B: (1-bA, 15-qtA).  Coverage: qt<=7 via A, qt>=8 via B, each once.

  // ---- staging source offsets (u16 units), pre-swizzled ----
  const int offK0 = (8 * w + (lane >> 4)) * 2048 + (((lane & 15) ^ ((lane >> 4) & 7)) * 8);
  const int offK1 = (8 * w + 4 + (lane >> 4)) * 2048 + (((lane & 15) ^ ((4 + (lane >> 4)) & 7)) * 8);
  const int offV0 = (16 * w + (lane >> 3)) * 4096 + (((lane & 7) ^ ((lane >> 3) & 7)) * 8);
  const int offV1 = offV0 + 8 * 4096;

  auto stage = [&](const u16* gK, const u16* gKlo, const u16* gV, int kt, int bp) {
    u16* B = &SMEM[bp * 24576];
    const int ka = kt * 131072;   // kt*64*2048
    const int va = kt * 64;
    gld16(gK + ka + offK0, B + 1024 * w);
    gld16(gK + ka + offK1, B + 1024 * w + 512);
    gld16(gKlo + ka + offK0, B + 8192 + 1024 * w);
    gld16(gKlo + ka + offK1, B + 8192 + 1024 * w + 512);
    gld16(gV + va + offV0, B + 16384 + 1024 * w);
    gld16(gV + va + offV1, B + 16384 + 1024 * w + 512);
  };

  int bufph = 0;
  // prime: task A tile 0
  {
    const u16* gK0 = Kh + ((size_t)(bA * 2048)) * 2048 + h * 128;
    const u16* gL0 = Kl + ((size_t)(bA * 2048)) * 2048 + h * 128;
    const u16* gV0 = Vt + (size_t)(h * 128) * 4096 + bA * 2048;
    stage(gK0, gL0, gV0, 0, 0);
  }

  for (int task = 0; task < 2; ++task) {
    const int qt = task ? 15 - qtA : qtA;
    const int bb = task ? 1 - bA : bA;
    const u16* gK0 = Kh + ((size_t)(bb * 2048)) * 2048 + h * 128;
    const u16* gL0 = Kl + ((size_t)(bb * 2048)) * 2048 + h * 128;
    const u16* gV0 = Vt + (size_t)(h * 128) * 4096 + bb * 2048;
    // next task's pointers (for cross-task prefetch)
    const int nb = 1 - bb;
    const u16* nK0 = Kh + ((size_t)(nb * 2048)) * 2048 + h * 128;
    const u16* nL0 = Kl + ((size_t)(nb * 2048)) * 2048 + h * 128;
    const u16* nV0 = Vt + (size_t)(h * 128) * 4096 + nb * 2048;

    const int q0 = qt * 128 + 32 * j;          // wave's first q row
    const int qg = q0 + l31;                   // this lane's q row
    // ---- Q fragments ----
    s16x8 qfh[8], qfl[8];
    {
      const size_t qbase = ((size_t)(bb * 2048 + qg)) * 2048 + h * 128 + 8 * hi;
#pragma unroll
      for (int s = 0; s < 8; ++s) {
        qfh[s] = *(const s16x8*)&Qh[qbase + 16 * s];
        qfl[s] = *(const s16x8*)&Ql[qbase + 16 * s];
      }
    }

    float m_run = -3.0e38f, l_run = 0.f;
    f32x16 o[4];
#pragma unroll
    for (int d = 0; d < 4; ++d)
#pragma unroll
      for (int r = 0; r < 16; ++r) o[d][r] = 0.f;

    const int nt = 2 * qt + 2;
    for (int kt = 0; kt < nt; ++kt) {
      // ---- issue next stage (stays in flight across barriers) ----
      bool staged = true;
      if (kt + 1 < nt)      stage(gK0, gL0, gV0, kt + 1, bufph ^ 1);
      else if (task == 0)   stage(nK0, nL0, nV0, 0, bufph ^ 1);
      else                  staged = false;
      if (staged) asm volatile("s_waitcnt vmcnt(6)" ::: "memory");
      else        asm volatile("s_waitcnt vmcnt(0)" ::: "memory");
      __builtin_amdgcn_sched_barrier(0);
      __builtin_amdgcn_s_barrier();
      __builtin_amdgcn_sched_barrier(0);

      const int kb0 = kt * 64 + 32 * kh;       // wave's k-half base
      const bool active = (q0 + 31) >= kb0;
      if (active) {
        const u16* Kb = &SMEM[bufph * 24576];
        const u16* Lb = Kb + 8192;
        const u16* Vb = Kb + 16384;
        // ---- S^T (wave's 32k x 32q block), split precision 3-term ----
        f32x16 acc;
#pragma unroll
        for (int r = 0; r < 16; ++r) acc[r] = 0.f;
        __builtin_amdgcn_s_setprio(1);
#pragma unroll
        for (int s = 0; s < 8; ++s) {
          const int col = 16 * s + 8 * hi;
          const s16x8 kha = *(const s16x8*)&Kb[((32 * kh + l31) * 128 + col) ^ swz];
          const s16x8 kla = *(const s16x8*)&Lb[((32 * kh + l31) * 128 + col) ^ swz];
          acc = MFMA32(kha, qfh[s], acc);
          acc = MFMA32(kla, qfh[s], acc);
          acc = MFMA32(kha, qfl[s], acc);
        }
        __builtin_amdgcn_s_setprio(0);

        // ---- causal mask + online softmax (lane-local, wave-private) ----
        const bool partial = (kb0 + 31) > q0;
        float mx = -3.0e38f;
#pragma unroll
        for (int r = 0; r < 16; ++r) {
          const int koff = (r & 3) + 8 * (r >> 2) + 4 * hi;
          float v = acc[r];
          if (partial && (kb0 + koff > qg)) v = -3.0e38f;
          acc[r] = v;
          mx = fmaxf(mx, v);
        }
        mx = fmaxf(mx, __shfl_xor(mx, 32));    // combine hi halves (same q)
        const float mn = fmaxf(m_run, mx);
        const float al = __expf(m_run - mn);
        m_run = mn;
        float rs = 0.f;
#pragma unroll
        for (int r = 0; r < 16; ++r) {
          const float e = __expf(acc[r] - mn);
          acc[r] = e;
          rs += e;
        }
        rs += __shfl_xor(rs, 32);
        l_run = l_run * al + rs;
#pragma unroll
        for (int d = 0; d < 4; ++d)
#pragma unroll
          for (int r = 0; r < 16; ++r) o[d][r] *= al;

        // ---- pack P -> PV B-fragments (cvt_pk + permlane32_swap) ----
        s16x8 pb[2];
#pragma unroll
        for (int tt = 0; tt < 2; ++tt) {
          const int q2A = 2 * tt;
          const float e0 = acc[4 * q2A + 0], e1 = acc[4 * q2A + 1];
          const float e2 = acc[4 * q2A + 2], e3 = acc[4 * q2A + 3];
          const float f0 = acc[4 * q2A + 4], f1 = acc[4 * q2A + 5];
          const float f2 = acc[4 * q2A + 6], f3 = acc[4 * q2A + 7];
          unsigned a0 = cvtpk_bf16(e0, e1);
          unsigned a1 = cvtpk_bf16(e2, e3);
          unsigned b0 = cvtpk_bf16(f0, f1);
          unsigned b1 = cvtpk_bf16(f2, f3);
          asm volatile("v_permlane32_swap_b32 %0, %1" : "+v"(a0), "+v"(b0));
          asm volatile("v_permlane32_swap_b32 %0, %1" : "+v"(a1), "+v"(b1));
          union { unsigned u[4]; s16x8 v; } pk;
          pk.u[0] = a0; pk.u[1] = a1; pk.u[2] = b0; pk.u[3] = b1;
          pb[tt] = pk.v;
        }

        // ---- O^T += V^T[:, wave's k-half] * P ----
        __builtin_amdgcn_s_setprio(1);
#pragma unroll
        for (int d = 0; d < 4; ++d) {
#pragma unroll
          for (int tt = 0; tt < 2; ++tt) {
            const s16x8 va = *(const s16x8*)
                &Vb[((32 * d + l31) * 64 + 16 * (2 * kh + tt) + 8 * hi) ^ swz];
            o[d] = MFMA32(va, pb[tt], o[d]);
          }
        }
        __builtin_amdgcn_s_setprio(0);
      }
      __builtin_amdgcn_s_barrier();
      bufph ^= 1;
    }

    // ======== epilogue: merge k-half wave pairs, normalize, store ========
    float* Sf = (float*)&SMEM[49152];          // 32KB scratch as f32[8192]
    // (1) m/l exchange
    Sf[w * 64 + lane] = m_run;
    Sf[512 + w * 64 + lane] = l_run;
    asm volatile("s_waitcnt lgkmcnt(0)" ::: "memory");
    __builtin_amdgcn_s_barrier();
    const float mOth = Sf[(w ^ 1) * 64 + lane];
    const float lOth = Sf[512 + (w ^ 1) * 64 + lane];
    const float mC = fmaxf(m_run, mOth);
    const float eS = __expf(m_run - mC);
    const float eO = __expf(mOth - mC);
    const float lC = eS * l_run + eO * lOth;
    // scale own partial O (odd waves hand over pre-scaled)
#pragma unroll
    for (int d = 0; d < 4; ++d)
#pragma unroll
      for (int r = 0; r < 16; ++r) o[d][r] *= eS;
    __builtin_amdgcn_s_barrier();              // m/l reads done before reuse
    // (2) O exchange: odd wave -> even wave, 2 rounds of 32KB
#pragma unroll
    for (int round = 0; round < 2; ++round) {
      if ((w >> 2) == round && kh == 1) {
        const int sl = j & 1;
#pragma unroll
        for (int d = 0; d < 4; ++d)
#pragma unroll
          for (int rr = 0; rr < 4; ++rr) {
            float4v c;
            c[0] = o[d][4 * rr + 0]; c[1] = o[d][4 * rr + 1];
            c[2] = o[d][4 * rr + 2]; c[3] = o[d][4 * rr + 3];
            const int cidx = 4 * (d * 4 + rr);
            *(float4v*)&Sf[sl * 4096 + ((lane * 64 + cidx) ^ ((lane & 7) << 2))] = c;
          }
      }
      asm volatile("s_waitcnt lgkmcnt(0)" ::: "memory");
      __builtin_amdgcn_s_barrier();
      if ((w >> 2) == round && kh == 0) {
        const int sl = j & 1;
#pragma unroll
        for (int d = 0; d < 4; ++d)
#pragma unroll
          for (int rr = 0; rr < 4; ++rr) {
            const int cidx = 4 * (d * 4 + rr);
            const float4v c =
                *(const float4v*)&Sf[sl * 4096 + ((lane * 64 + cidx) ^ ((lane & 7) << 2))];
            o[d][4 * rr + 0] += c[0]; o[d][4 * rr + 1] += c[1];
            o[d][4 * rr + 2] += c[2]; o[d][4 * rr + 3] += c[3];
          }
      }
      __builtin_amdgcn_s_barrier();
    }
    // (3) even waves: normalize + transposed bf16 write to Os
    u16* Os = &SMEM[49152];                    // [128][128] u16, swizzled
    if (kh == 0) {
      const float inv_l = 1.0f / lC;
      const int rl = 32 * j + l31;
#pragma unroll
      for (int d = 0; d < 4; ++d)
#pragma unroll
        for (int r = 0; r < 16; r += 2) {
          const int dd = 32 * d + (r & 3) + 8 * (r >> 2) + 4 * hi;
          const unsigned pr = cvtpk_bf16(o[d][r] * inv_l, o[d][r + 1] * inv_l);
          *(unsigned*)&Os[(rl * 128 + dd) ^ ((rl & 7) << 3)] = pr;
        }
    }
    asm volatile("s_waitcnt lgkmcnt(0)" ::: "memory");
    __builtin_amdgcn_s_barrier();
    // (4) coalesced store, all 8 waves
    {
      const int rr = t >> 2, cb = (t & 3) * 32;
      const size_t ob =
          ((size_t)(bb * 2048 + qt * 128 + rr)) * 2048 + h * 128 + cb;
#pragma unroll
      for (int p = 0; p < 4; ++p)
        *(u16x8*)&Ctx[ob + 8 * p] =
            *(const u16x8*)&Os[(rr * 128 + cb + 8 * p) ^ ((rr & 7) << 3)];
    }
    asm volatile("s_waitcnt lgkmcnt(0)" ::: "memory");
    __builtin_amdgcn_s_barrier();
  }
}

// ---------------------------------------------------------------------------
extern "C" void kernel_launch(void* const* d_in, const int* in_sizes, int n_in,
                              void* d_out, int out_size, void* d_ws, size_t ws_size,
                              hipStream_t stream) {
  const float* x  = (const float*)d_in[0];
  const float* Wq = (const float*)d_in[1];
  const float* Wk = (const float*)d_in[2];
  const float* Wv = (const float*)d_in[3];
  const float* Wo = (const float*)d_in[4];
  float* out = (float*)d_out;

  char* ws = (char*)d_ws;
  size_t off = 0;
  auto alloc = [&](size_t bytes) {
    char* p = ws + off;
    off += (bytes + 255) & ~(size_t)255;
    return p;
  };
  const size_t XE = (size_t)4096 * 2048;   // B*S x H elements
  const size_t WE = (size_t)2048 * 2048;

  u16* xh  = (u16*)alloc(XE * 2);
  u16* xl  = (u16*)alloc(XE * 2);
  u16* Wqh = (u16*)alloc(WE * 2);
  u16* Wql = (u16*)alloc(WE * 2);
  u16* Wkh = (u16*)alloc(WE * 2);
  u16* Wkl = (u16*)alloc(WE * 2);
  u16* Wvh = (u16*)alloc(WE * 2);
  u16* Woh = (u16*)alloc(WE * 2);
  u16* Qhb = (u16*)alloc(XE * 2);
  u16* Qlb = (u16*)alloc(XE * 2);
  u16* Khb = (u16*)alloc(XE * 2);
  u16* Klb = (u16*)alloc(XE * 2);
  u16* Vtb = (u16*)alloc(XE * 2);   // V^T: [2048 dims][4096 seq]
  u16* Ctxb = (u16*)alloc(XE * 2);
  float* cosT = (float*)alloc((size_t)2048 * 64 * 4);
  float* sinT = (float*)alloc((size_t)2048 * 64 * 4);
  (void)ws_size;  // requires ~170 MB of workspace
  (void)in_sizes; (void)n_in; (void)out_size;

  // 1) precision split + RoPE tables
  split_bf16<<<8192, 256, 0, stream>>>(x, xh, xl, (int)(XE / 4));
  split_bf16<<<4096, 256, 0, stream>>>(Wq, Wqh, Wql, (int)(WE / 4));
  split_bf16<<<4096, 256, 0, stream>>>(Wk, Wkh, Wkl, (int)(WE / 4));
  split_bf16<<<4096, 256, 0, stream>>>(Wv, Wvh, nullptr, (int)(WE / 4));
  split_bf16<<<4096, 256, 0, stream>>>(Wo, Woh, nullptr, (int)(WE / 4));
  rope_tab<<<512, 256, 0, stream>>>(cosT, sinT);

  // 2) fused Q+K projection (shared A staging, shared RoPE tables)
  gemm_qk<<<dim3(16, 16), 512, 0, stream>>>(
      xh, xl, Wqh, Wql, Wkh, Wkl, Qhb, Qlb, Khb, Klb, cosT, sinT,
      11.313708498984760f, 4096, 2048, 2048);
  // V^T = Wv * x^T :  A=Wv (M=2048 dims), B=x (N=4096 seq)
  gemm8<1, 2, 0, 32><<<dim3(32, 8), 512, 0, stream>>>(
      Wvh, nullptr, xh, nullptr, nullptr, Vtb, nullptr, nullptr, nullptr,
      1.0f, 2048, 4096, 2048);

  // 3) causal flash attention (de-duped task map, k-split wave pairs)
  attn<<<dim3(8, 16, 2), 512, 0, stream>>>(Qhb, Qlb, Khb, Klb, Vtb, Ctxb);

  // 4) output projection -> fp32 d_out
  gemm8<1, 0, 0, 16><<<dim3(16, 16), 512, 0, stream>>>(
      Ctxb, nullptr, Woh, nullptr, out, nullptr, nullptr, nullptr, nullptr,
      1.0f, 4096, 2048, 2048);
}

// Round 10
// 501.200 us; speedup vs baseline: 1.0553x; 1.0371x over previous
//
#include <hip/hip_runtime.h>
#include <cmath>

// ============================================================================
// AutoregressiveGroupQuerySelfAttention  (B=2, S=2048, H=2048, nH=16, D=128)
//
// Round 14: tail optimization (gemm_qk phase lever closed at ~190us/50%).
//  - gemm1k: 1-term GEMM at BK=64 (32 steps, 16 MFMA/wave/step vs 8 at
//    BK=32 -> compute phase doubles against fixed per-step barrier cost).
//    Double-buffered 96KB LDS, CORRECT counted vmcnt(6) (old gemm8 depth-2
//    vmcnt(12|6) was a no-op: outstanding == N when it executed).
//    Used for V^T (OMODE=2) and Wo (OMODE=0). gemm8 deleted.
//  - split_all: 5 split_bf16 launches fused into one (grid 4096x6).
//  - gemm_qk (R13 fine-interleaved 2-phase) and attn (R8) unchanged.
// ============================================================================

typedef unsigned short u16;
typedef __attribute__((ext_vector_type(4))) float  f32x4;
typedef __attribute__((ext_vector_type(16))) float f32x16;
typedef __attribute__((ext_vector_type(4))) float  float4v;
typedef __attribute__((ext_vector_type(4))) unsigned short u16x4;
typedef __attribute__((ext_vector_type(8))) unsigned short u16x8;
typedef __attribute__((ext_vector_type(8))) short s16x8;

__device__ __forceinline__ u16 f2bf(float f) {
  unsigned u = __float_as_uint(f);
  u += 0x7FFFu + ((u >> 16) & 1u);            // RNE; inputs are finite
  return (u16)(u >> 16);
}
__device__ __forceinline__ float bf2f(u16 h) {
  return __uint_as_float(((unsigned)h) << 16);
}
__device__ __forceinline__ f32x16 MFMA32(s16x8 a, s16x8 b, f32x16 c) {
  return __builtin_amdgcn_mfma_f32_32x32x16_bf16(a, b, c, 0, 0, 0);
}
__device__ __forceinline__ unsigned cvtpk_bf16(float lo, float hi) {
  unsigned r;
  asm("v_cvt_pk_bf16_f32 %0, %1, %2" : "=v"(r) : "v"(lo), "v"(hi));
  return r;
}
// async global->LDS, 16B per lane; LDS dest = wave-uniform base + lane*16
__device__ __forceinline__ void gld16(const void* g, void* s) {
  __builtin_amdgcn_global_load_lds(
      (const __attribute__((address_space(1))) void*)g,
      (__attribute__((address_space(3))) void*)s, 16, 0, 0);
}

// ---------------------------------------------------------------------------
// Fused precision split: y-slot selects tensor. x spans slots 0-1 (hi+lo);
// Wq,Wk slots 2-3 (hi+lo); Wv,Wo slots 4-5 (hi only). WE/4 = 1<<20 per slot.
// ---------------------------------------------------------------------------
__global__ void split_all(const float* __restrict__ x, const float* __restrict__ Wq,
                          const float* __restrict__ Wk, const float* __restrict__ Wv,
                          const float* __restrict__ Wo,
                          u16* __restrict__ xh, u16* __restrict__ xl,
                          u16* __restrict__ Wqh, u16* __restrict__ Wql,
                          u16* __restrict__ Wkh, u16* __restrict__ Wkl,
                          u16* __restrict__ Wvh, u16* __restrict__ Woh) {
  const int y = blockIdx.y;
  const int base = blockIdx.x * 256 + threadIdx.x;   // [0, 1<<20)
  const float* src; u16* dh; u16* dl = nullptr; int i = base;
  if (y == 0)      { src = x;  dh = xh;  dl = xl; }
  else if (y == 1) { src = x;  dh = xh;  dl = xl; i = base + (1 << 20); }
  else if (y == 2) { src = Wq; dh = Wqh; dl = Wql; }
  else if (y == 3) { src = Wk; dh = Wkh; dl = Wkl; }
  else if (y == 4) { src = Wv; dh = Wvh; }
  else             { src = Wo; dh = Woh; }
  float4v v = ((const float4v*)src)[i];
  u16x4 hv, lv;
#pragma unroll
  for (int j = 0; j < 4; ++j) {
    float f = v[j];
    u16 h = f2bf(f);
    hv[j] = h;
    lv[j] = f2bf(f - bf2f(h));
  }
  ((u16x4*)dh)[i] = hv;
  if (dl) ((u16x4*)dl)[i] = lv;
}

// ---------------------------------------------------------------------------
// RoPE tables in fp64.
// ---------------------------------------------------------------------------
__global__ void rope_tab(float* __restrict__ cosT, float* __restrict__ sinT) {
  int idx = blockIdx.x * 256 + threadIdx.x;   // 2048*64
  int i = idx & 63, s = idx >> 6;
  double invf = pow(10000.0, -(double)i / 64.0);
  double ang = (double)s * invf;
  cosT[idx] = (float)cos(ang);
  sinT[idx] = (float)sin(ang);
}

// ---------------------------------------------------------------------------
// gemm_qk: fused Q/K projection.  (R13 structure, unchanged.)
// ---------------------------------------------------------------------------
__global__ __launch_bounds__(512, 1)
void gemm_qk(const u16* __restrict__ xh, const u16* __restrict__ xl,
             const u16* __restrict__ Wqh, const u16* __restrict__ Wql,
             const u16* __restrict__ Wkh, const u16* __restrict__ Wkl,
             u16* __restrict__ Qh, u16* __restrict__ Ql,
             u16* __restrict__ Kh, u16* __restrict__ Kl,
             const float* __restrict__ cosT, const float* __restrict__ sinT,
             float qscale, int M, int N, int K) {
  __shared__ u16 SM[2 * 32768];                 // 128 KB
  const int t = threadIdx.x;
  const int w = t >> 6, lane = t & 63;
  const int l31 = lane & 31, hi = lane >> 5;
  const int wm = w >> 1, wn = w & 1;

  // ---- XCD-locality remap (grid.x = 16 -> 2 bn per XCD) ----
  const int bid = (int)blockIdx.x + 16 * (int)blockIdx.y;
  const int xcd = bid & 7, slot = bid >> 3;
  const int bn = 2 * xcd + (slot & 1);
  const int bm = slot >> 1;

  const size_t arow0 = (size_t)bm * 256, brow0 = (size_t)bn * 128;

  // ---- staging: linear LDS dest, pre-swizzled global source ----
  const int pA0 = 128 * w + lane;
  const int pA1 = pA0 + 64;
  const int pB0 = 64 * w + lane;
  const int qA0 = pA0 ^ ((pA0 >> 3) & 7);
  const int qA1 = pA1 ^ ((pA1 >> 3) & 7);
  const int qB0 = pB0 ^ ((pB0 >> 3) & 7);
  const size_t gA0 = (arow0 + (qA0 >> 2)) * (size_t)K + (qA0 & 3) * 8;
  const size_t gA1 = (arow0 + (qA1 >> 2)) * (size_t)K + (qA1 & 3) * 8;
  const size_t gB0 = (brow0 + (qB0 >> 2)) * (size_t)K + (qB0 & 3) * 8;

  auto stageA = [&](int k0, int bp) {        // A (x) hi+lo : 4 loads
    u16* P = &SM[bp * 32768];
    gld16(&xh[gA0 + k0], P + 1024 * w);
    gld16(&xh[gA1 + k0], P + 1024 * w + 512);
    gld16(&xl[gA0 + k0], P + 8192 + 1024 * w);
    gld16(&xl[gA1 + k0], P + 8192 + 1024 * w + 512);
  };
  auto stageB = [&](int k0, int bp) {        // B (Wq,Wk) hi+lo : 4 loads
    u16* P = &SM[bp * 32768];
    gld16(&Wqh[gB0 + k0], P + 16384 + 512 * w);
    gld16(&Wql[gB0 + k0], P + 20480 + 512 * w);
    gld16(&Wkh[gB0 + k0], P + 24576 + 512 * w);
    gld16(&Wkl[gB0 + k0], P + 28672 + 512 * w);
  };

  auto aoff = [&](int fm, int ks) {
    int q = ((64 * wm + 32 * fm + l31) << 2) | (2 * ks + hi);
    q ^= (q >> 3) & 7;
    return q * 8;
  };
  auto boff = [&](int fn, int ks) {
    int q = ((32 * wn + 64 * fn + l31) << 2) | (2 * ks + hi);
    q ^= (q >> 3) & 7;
    return q * 8;
  };

  f32x16 accq[2][2], acck[2][2];
#pragma unroll
  for (int fm = 0; fm < 2; ++fm)
#pragma unroll
    for (int fn = 0; fn < 2; ++fn)
#pragma unroll
      for (int r = 0; r < 16; ++r) { accq[fm][fn][r] = 0.f; acck[fm][fn][r] = 0.f; }

  const int NK = K >> 5;
  stageA(0, 0);
  stageB(0, 0);
  asm volatile("s_waitcnt vmcnt(0)" ::: "memory");
  __builtin_amdgcn_sched_barrier(0);
  __builtin_amdgcn_s_barrier();
  __builtin_amdgcn_sched_barrier(0);

  int bp = 0;
  for (int kt = 0; kt < NK; ++kt) {
    const u16* P = &SM[bp * 32768];
    const bool more = (kt + 1 < NK);

    // ======== phase A: reads a+bq, issue A-gloads, 24 Q-MFMAs ========
    s16x8 a_h[2][2], a_l[2][2];
    {
      s16x8 bq_h[2][2], bq_l[2][2];
#pragma unroll
      for (int ks = 0; ks < 2; ++ks)
#pragma unroll
        for (int fm = 0; fm < 2; ++fm) {
          a_h[ks][fm] = *(const s16x8*)&P[aoff(fm, ks)];
          a_l[ks][fm] = *(const s16x8*)&P[8192 + aoff(fm, ks)];
        }
#pragma unroll
      for (int ks = 0; ks < 2; ++ks)
#pragma unroll
        for (int fn = 0; fn < 2; ++fn) {
          bq_h[ks][fn] = *(const s16x8*)&P[16384 + boff(fn, ks)];
          bq_l[ks][fn] = *(const s16x8*)&P[20480 + boff(fn, ks)];
        }
      if (more) stageA((kt + 1) * 32, bp ^ 1);
      __builtin_amdgcn_sched_barrier(0);
      __builtin_amdgcn_s_barrier();
      asm volatile("s_waitcnt lgkmcnt(0)" ::: "memory");
      __builtin_amdgcn_sched_barrier(0);
      __builtin_amdgcn_s_setprio(1);
#pragma unroll
      for (int ks = 0; ks < 2; ++ks)
#pragma unroll
        for (int fm = 0; fm < 2; ++fm)
#pragma unroll
          for (int fn = 0; fn < 2; ++fn) {
            accq[fm][fn] = MFMA32(a_h[ks][fm], bq_h[ks][fn], accq[fm][fn]);
            accq[fm][fn] = MFMA32(a_h[ks][fm], bq_l[ks][fn], accq[fm][fn]);
            accq[fm][fn] = MFMA32(a_l[ks][fm], bq_h[ks][fn], accq[fm][fn]);
          }
      __builtin_amdgcn_s_setprio(0);
      __builtin_amdgcn_sched_barrier(0);
      __builtin_amdgcn_s_barrier();
      __builtin_amdgcn_sched_barrier(0);
    }

    // ======== phase B: reads bk, issue B-gloads, 24 K-MFMAs ========
    {
      s16x8 bk_h[2][2], bk_l[2][2];
#pragma unroll
      for (int ks = 0; ks < 2; ++ks)
#pragma unroll
        for (int fn = 0; fn < 2; ++fn) {
          bk_h[ks][fn] = *(const s16x8*)&P[24576 + boff(fn, ks)];
          bk_l[ks][fn] = *(const s16x8*)&P[28672 + boff(fn, ks)];
        }
      if (more) stageB((kt + 1) * 32, bp ^ 1);
      __builtin_amdgcn_sched_barrier(0);
      __builtin_amdgcn_s_barrier();
      asm volatile("s_waitcnt lgkmcnt(0)" ::: "memory");
      __builtin_amdgcn_sched_barrier(0);
      __builtin_amdgcn_s_setprio(1);
#pragma unroll
      for (int ks = 0; ks < 2; ++ks)
#pragma unroll
        for (int fm = 0; fm < 2; ++fm)
#pragma unroll
          for (int fn = 0; fn < 2; ++fn) {
            acck[fm][fn] = MFMA32(a_h[ks][fm], bk_h[ks][fn], acck[fm][fn]);
            acck[fm][fn] = MFMA32(a_h[ks][fm], bk_l[ks][fn], acck[fm][fn]);
            acck[fm][fn] = MFMA32(a_l[ks][fm], bk_h[ks][fn], acck[fm][fn]);
          }
      __builtin_amdgcn_s_setprio(0);
      __builtin_amdgcn_sched_barrier(0);
      asm volatile("s_waitcnt vmcnt(0)" ::: "memory");
      __builtin_amdgcn_s_barrier();
      __builtin_amdgcn_sched_barrier(0);
    }
    bp ^= 1;
  }

  // ---- epilogue: RoPE both outputs, shared tables ----
  const int hd = 32 * wn + l31;
#pragma unroll
  for (int fm = 0; fm < 2; ++fm)
#pragma unroll
    for (int r = 0; r < 16; ++r) {
      const int row = bm * 256 + 64 * wm + 32 * fm + (r & 3) + 8 * (r >> 2) + 4 * hi;
      const int s = row & 2047;
      const float cs = cosT[s * 64 + hd], sn = sinT[s * 64 + hd];
      const size_t p1 = (size_t)row * N + bn * 128 + hd;
      {
        const float q1 = accq[fm][0][r], q2 = accq[fm][1][r];
        const float o1 = (q1 * cs - q2 * sn) * qscale;
        const float o2 = (q2 * cs + q1 * sn) * qscale;
        const u16 h1 = f2bf(o1);
        Qh[p1] = h1; Ql[p1] = f2bf(o1 - bf2f(h1));
        const u16 h2 = f2bf(o2);
        Qh[p1 + 64] = h2; Ql[p1 + 64] = f2bf(o2 - bf2f(h2));
      }
      {
        const float k1 = acck[fm][0][r], k2 = acck[fm][1][r];
        const float o1 = k1 * cs - k2 * sn;
        const float o2 = k2 * cs + k1 * sn;
        const u16 h1 = f2bf(o1);
        Kh[p1] = h1; Kl[p1] = f2bf(o1 - bf2f(h1));
        const u16 h2 = f2bf(o2);
        Kh[p1 + 64] = h2; Kl[p1 + 64] = f2bf(o2 - bf2f(h2));
      }
    }
}

// ---------------------------------------------------------------------------
// gemm1k: 1-term bf16 GEMM, C(MxN) = A(MxK) * B(NxK)^T, BK=64.
// OMODE: 0 fp32 out, 2 bf16 out. GX = grid.x (XCD remap PER=GX/8).
// 256x128 tile, 512 thr = 8 waves (wm=w>>1, wn=w&1), per-wave 64x64.
// LDS per buffer (u16): A[0,16384) = 256x64, B[16384,24576) = 128x64;
// 2 bufs = 96KB. Staging 6 gld16/wave/stage, counted vmcnt(6) (drains the
// PREVIOUS stage exactly). 16B-chunk involution swizzle both sides.
// Per step: 16 ds_read_b128 + 16 MFMAs per wave (2x the BK=32 density).
// ---------------------------------------------------------------------------
template <int OMODE, int GX>
__global__ __launch_bounds__(512, 1)
void gemm1k(const u16* __restrict__ Ah, const u16* __restrict__ Bh,
            float* __restrict__ Cf, u16* __restrict__ Ch,
            int M, int N, int K) {
  constexpr int PER = GX / 8;
  constexpr int PSH = (PER == 2) ? 1 : 2;
  static_assert(PER == 2 || PER == 4, "grid.x must be 16 or 32");
  __shared__ u16 SM[2 * 24576];               // 96 KB
  const int t = threadIdx.x;
  const int w = t >> 6, lane = t & 63;
  const int l31 = lane & 31, hi = lane >> 5;
  const int wm = w >> 1, wn = w & 1;

  const int bid = (int)blockIdx.x + GX * (int)blockIdx.y;
  const int xcd = bid & 7, slot = bid >> 3;
  const int bn = PER * xcd + (slot & (PER - 1));
  const int bm = slot >> PSH;
  const size_t arow0 = (size_t)bm * 256, brow0 = (size_t)bn * 128;

  // staging chunk p -> swizzled global chunk q (8 chunks per 64-col row)
  size_t gA[4], gB[2];
#pragma unroll
  for (int i = 0; i < 4; ++i) {
    const int p = 512 * i + 64 * w + lane;
    const int q = p ^ ((p >> 3) & 7);
    gA[i] = (arow0 + (q >> 3)) * (size_t)K + (q & 7) * 8;
  }
#pragma unroll
  for (int i = 0; i < 2; ++i) {
    const int p = 512 * i + 64 * w + lane;
    const int q = p ^ ((p >> 3) & 7);
    gB[i] = (brow0 + (q >> 3)) * (size_t)K + (q & 7) * 8;
  }

  auto stage = [&](int k0, int bp) {
    u16* P = &SM[bp * 24576];
#pragma unroll
    for (int i = 0; i < 4; ++i)
      gld16(&Ah[gA[i] + k0], P + 4096 * i + 512 * w);
#pragma unroll
    for (int i = 0; i < 2; ++i)
      gld16(&Bh[gB[i] + k0], P + 16384 + 4096 * i + 512 * w);
  };
  auto aoff = [&](int fm, int ks) {
    int g = ((64 * wm + 32 * fm + l31) << 3) | (2 * ks + hi);
    g ^= (g >> 3) & 7;
    return g * 8;
  };
  auto boff = [&](int fn, int ks) {
    int g = ((32 * wn + 64 * fn + l31) << 3) | (2 * ks + hi);
    g ^= (g >> 3) & 7;
    return 16384 + g * 8;
  };

  f32x16 acc[2][2];
#pragma unroll
  for (int fm = 0; fm < 2; ++fm)
#pragma unroll
    for (int fn = 0; fn < 2; ++fn)
#pragma unroll
      for (int r = 0; r < 16; ++r) acc[fm][fn][r] = 0.f;

  const int NK = K >> 6;
  stage(0, 0);
  int bp = 0;
  for (int kt = 0; kt < NK; ++kt) {
    if (kt + 1 < NK) {
      stage((kt + 1) * 64, bp ^ 1);
      asm volatile("s_waitcnt vmcnt(6)" ::: "memory");   // drains stage(kt)
    } else {
      asm volatile("s_waitcnt vmcnt(0)" ::: "memory");
    }
    __builtin_amdgcn_sched_barrier(0);
    __builtin_amdgcn_s_barrier();
    __builtin_amdgcn_sched_barrier(0);

    const u16* P = &SM[bp * 24576];
    __builtin_amdgcn_s_setprio(1);
#pragma unroll
    for (int ks = 0; ks < 4; ++ks) {
      s16x8 a_h[2], b_h[2];
#pragma unroll
      for (int fm = 0; fm < 2; ++fm) a_h[fm] = *(const s16x8*)&P[aoff(fm, ks)];
#pragma unroll
      for (int fn = 0; fn < 2; ++fn) b_h[fn] = *(const s16x8*)&P[boff(fn, ks)];
#pragma unroll
      for (int fm = 0; fm < 2; ++fm)
#pragma unroll
        for (int fn = 0; fn < 2; ++fn)
          acc[fm][fn] = MFMA32(a_h[fm], b_h[fn], acc[fm][fn]);
    }
    __builtin_amdgcn_s_setprio(0);
    __builtin_amdgcn_s_barrier();
    bp ^= 1;
  }

  // ---- epilogue ----
#pragma unroll
  for (int fm = 0; fm < 2; ++fm)
#pragma unroll
    for (int fn = 0; fn < 2; ++fn)
#pragma unroll
      for (int r = 0; r < 16; ++r) {
        const int row = bm * 256 + 64 * wm + 32 * fm + (r & 3) + 8 * (r >> 2) + 4 * hi;
        const int col = bn * 128 + 32 * wn + 64 * fn + l31;
        const float v = acc[fm][fn][r];
        if constexpr (OMODE == 0) {
          Cf[(size_t)row * N + col] = v;
        } else {
          Ch[(size_t)row * N + col] = f2bf(v);
        }
      }
}

// ---------------------------------------------------------------------------
// Flash attention, causal, 32x32x16 swapped-operand MFMA, counted-vmcnt
// double-buffered pipeline, QBLK=128, k-split wave pairs.  (unchanged R8)
// ---------------------------------------------------------------------------
__global__ __launch_bounds__(512, 2)
void attn(const u16* __restrict__ Qh, const u16* __restrict__ Ql,
          const u16* __restrict__ Kh, const u16* __restrict__ Kl,
          const u16* __restrict__ Vt, u16* __restrict__ Ctx) {
  __shared__ u16 SMEM[65536];               // 128 KB
  // buf p at u16 p*24576: Kh [0,8192) Kl [8192,16384) V [16384,24576)
  // scratch at u16 49152 (32 KB): m/l exchange, then O exchange, then Os

  const int t = threadIdx.x;
  const int w = t >> 6, lane = t & 63;
  const int l31 = lane & 31, hi = lane >> 5;
  const int swz = (l31 & 7) << 3;
  const int j = w >> 1, kh = w & 1;         // q-slice, k-half

  // ---- XCD remap: 16 blocks of a head on one XCD; unique task pairs ----
  const int bid = (int)blockIdx.x + 8 * (int)blockIdx.y + 128 * (int)blockIdx.z;
  const int xcd = bid & 7, slot = bid >> 3;          // slot 0..31
  const int h = xcd * 2 + (slot >> 4);
  const int rem = slot & 15;
  const int qtA = rem & 7, bA = rem >> 3;            // task A: (bA, qtA)
  // task B: (1-bA, 15-qtA).  Coverage: qt<=7 via A, qt>=8 via B, each once.

  // ---- staging source offsets (u16 units), pre-swizzled ----
  const int offK0 = (8 * w + (lane >> 4)) * 2048 + (((lane & 15) ^ ((lane >> 4) & 7)) * 8);
  const int offK1 = (8 * w + 4 + (lane >> 4)) * 2048 + (((lane & 15) ^ ((4 + (lane >> 4)) & 7)) * 8);
  const int offV0 = (16 * w + (lane >> 3)) * 4096 + (((lane & 7) ^ ((lane >> 3) & 7)) * 8);
  const int offV1 = offV0 + 8 * 4096;

  auto stage = [&](const u16* gK, const u16* gKlo, const u16* gV, int kt, int bp) {
    u16* B = &SMEM[bp * 24576];
    const int ka = kt * 131072;   // kt*64*2048
    const int va = kt * 64;
    gld16(gK + ka + offK0, B + 1024 * w);
    gld16(gK + ka + offK1, B + 1024 * w + 512);
    gld16(gKlo + ka + offK0, B + 8192 + 1024 * w);
    gld16(gKlo + ka + offK1, B + 8192 + 1024 * w + 512);
    gld16(gV + va + offV0, B + 16384 + 1024 * w);
    gld16(gV + va + offV1, B + 16384 + 1024 * w + 512);
  };

  int bufph = 0;
  // prime: task A tile 0
  {
    const u16* gK0 = Kh + ((size_t)(bA * 2048)) * 2048 + h * 128;
    const u16* gL0 = Kl + ((size_t)(bA * 2048)) * 2048 + h * 128;
    const u16* gV0 = Vt + (size_t)(h * 128) * 4096 + bA * 2048;
    stage(gK0, gL0, gV0, 0, 0);
  }

  for (int task = 0; task < 2; ++task) {
    const int qt = task ? 15 - qtA : qtA;
    const int bb = task ? 1 - bA : bA;
    const u16* gK0 = Kh + ((size_t)(bb * 2048)) * 2048 + h * 128;
    const u16* gL0 = Kl + ((size_t)(bb * 2048)) * 2048 + h * 128;
    const u16* gV0 = Vt + (size_t)(h * 128) * 4096 + bb * 2048;
    // next task's pointers (for cross-task prefetch)
    const int nb = 1 - bb;
    const u16* nK0 = Kh + ((size_t)(nb * 2048)) * 2048 + h * 128;
    const u16* nL0 = Kl + ((size_t)(nb * 2048)) * 2048 + h * 128;
    const u16* nV0 = Vt + (size_t)(h * 128) * 4096 + nb * 2048;

    const int q0 = qt * 128 + 32 * j;          // wave's first q row
    const int qg = q0 + l31;                   // this lane's q row
    // ---- Q fragments ----
    s16x8 qfh[8], qfl[8];
    {
      const size_t qbase = ((size_t)(bb * 2048 + qg)) * 2048 + h * 128 + 8 * hi;
#pragma unroll
      for (int s = 0; s < 8; ++s) {
        qfh[s] = *(const s16x8*)&Qh[qbase + 16 * s];
        qfl[s] = *(const s16x8*)&Ql[qbase + 16 * s];
      }
    }

    float m_run = -3.0e38f, l_run = 0.f;
    f32x16 o[4];
#pragma unroll
    for (int d = 0; d < 4; ++d)
#pragma unroll
      for (int r = 0; r < 16; ++r) o[d][r] = 0.f;

    const int nt = 2 * qt + 2;
    for (int kt = 0; kt < nt; ++kt) {
      // ---- issue next stage (stays in flight across barriers) ----
      bool staged = true;
      if (kt + 1 < nt)      stage(gK0, gL0, gV0, kt + 1, bufph ^ 1);
      else if (task == 0)   stage(nK0, nL0, nV0, 0, bufph ^ 1);
      else                  staged = false;
      if (staged) asm volatile("s_waitcnt vmcnt(6)" ::: "memory");
      else        asm volatile("s_waitcnt vmcnt(0)" ::: "memory");
      __builtin_amdgcn_sched_barrier(0);
      __builtin_amdgcn_s_barrier();
      __builtin_amdgcn_sched_barrier(0);

      const int kb0 = kt * 64 + 32 * kh;       // wave's k-half base
      const bool active = (q0 + 31) >= kb0;
      if (active) {
        const u16* Kb = &SMEM[bufph * 24576];
        const u16* Lb = Kb + 8192;
        const u16* Vb = Kb + 16384;
        // ---- S^T (wave's 32k x 32q block), split precision 3-term ----
        f32x16 acc;
#pragma unroll
        for (int r = 0; r < 16; ++r) acc[r] = 0.f;
        __builtin_amdgcn_s_setprio(1);
#pragma unroll
        for (int s = 0; s < 8; ++s) {
          const int col = 16 * s + 8 * hi;
          const s16x8 kha = *(const s16x8*)&Kb[((32 * kh + l31) * 128 + col) ^ swz];
          const s16x8 kla = *(const s16x8*)&Lb[((32 * kh + l31) * 128 + col) ^ swz];
          acc = MFMA32(kha, qfh[s], acc);
          acc = MFMA32(kla, qfh[s], acc);
          acc = MFMA32(kha, qfl[s], acc);
        }
        __builtin_amdgcn_s_setprio(0);

        // ---- causal mask + online softmax (lane-local, wave-private) ----
        const bool partial = (kb0 + 31) > q0;
        float mx = -3.0e38f;
#pragma unroll
        for (int r = 0; r < 16; ++r) {
          const int koff = (r & 3) + 8 * (r >> 2) + 4 * hi;
          float v = acc[r];
          if (partial && (kb0 + koff > qg)) v = -3.0e38f;
          acc[r] = v;
          mx = fmaxf(mx, v);
        }
        mx = fmaxf(mx, __shfl_xor(mx, 32));    // combine hi halves (same q)
        const float mn = fmaxf(m_run, mx);
        const float al = __expf(m_run - mn);
        m_run = mn;
        float rs = 0.f;
#pragma unroll
        for (int r = 0; r < 16; ++r) {
          const float e = __expf(acc[r] - mn);
          acc[r] = e;
          rs += e;
        }
        rs += __shfl_xor(rs, 32);
        l_run = l_run * al + rs;
#pragma unroll
        for (int d = 0; d < 4; ++d)
#pragma unroll
          for (int r = 0; r < 16; ++r) o[d][r] *= al;

        // ---- pack P -> PV B-fragments (cvt_pk + permlane32_swap) ----
        s16x8 pb[2];
#pragma unroll
        for (int tt = 0; tt < 2; ++tt) {
          const int q2A = 2 * tt;
          const float e0 = acc[4 * q2A + 0], e1 = acc[4 * q2A + 1];
          const float e2 = acc[4 * q2A + 2], e3 = acc[4 * q2A + 3];
          const float f0 = acc[4 * q2A + 4], f1 = acc[4 * q2A + 5];
          const float f2 = acc[4 * q2A + 6], f3 = acc[4 * q2A + 7];
          unsigned a0 = cvtpk_bf16(e0, e1);
          unsigned a1 = cvtpk_bf16(e2, e3);
          unsigned b0 = cvtpk_bf16(f0, f1);
          unsigned b1 = cvtpk_bf16(f2, f3);
          asm volatile("v_permlane32_swap_b32 %0, %1" : "+v"(a0), "+v"(b0));
          asm volatile("v_permlane32_swap_b32 %0, %1" : "+v"(a1), "+v"(b1));
          union { unsigned u[4]; s16x8 v; } pk;
          pk.u[0] = a0; pk.u[1] = a1; pk.u[2] = b0; pk.u[3] = b1;
          pb[tt] = pk.v;
        }

        // ---- O^T += V^T[:, wave's k-half] * P ----
        __builtin_amdgcn_s_setprio(1);
#pragma unroll
        for (int d = 0; d < 4; ++d) {
#pragma unroll
          for (int tt = 0; tt < 2; ++tt) {
            const s16x8 va = *(const s16x8*)
                &Vb[((32 * d + l31) * 64 + 16 * (2 * kh + tt) + 8 * hi) ^ swz];
            o[d] = MFMA32(va, pb[tt], o[d]);
          }
        }
        __builtin_amdgcn_s_setprio(0);
      }
      __builtin_amdgcn_s_barrier();
      bufph ^= 1;
    }

    // ======== epilogue: merge k-half wave pairs, normalize, store ========
    float* Sf = (float*)&SMEM[49152];          // 32KB scratch as f32[8192]
    // (1) m/l exchange
    Sf[w * 64 + lane] = m_run;
    Sf[512 + w * 64 + lane] = l_run;
    asm volatile("s_waitcnt lgkmcnt(0)" ::: "memory");
    __builtin_amdgcn_s_barrier();
    const float mOth = Sf[(w ^ 1) * 64 + lane];
    const float lOth = Sf[512 + (w ^ 1) * 64 + lane];
    const float mC = fmaxf(m_run, mOth);
    const float eS = __expf(m_run - mC);
    const float eO = __expf(mOth - mC);
    const float lC = eS * l_run + eO * lOth;
    // scale own partial O (odd waves hand over pre-scaled)
#pragma unroll
    for (int d = 0; d < 4; ++d)
#pragma unroll
      for (int r = 0; r < 16; ++r) o[d][r] *= eS;
    __builtin_amdgcn_s_barrier();              // m/l reads done before reuse
    // (2) O exchange: odd wave -> even wave, 2 rounds of 32KB
#pragma unroll
    for (int round = 0; round < 2; ++round) {
      if ((w >> 2) == round && kh == 1) {
        const int sl = j & 1;
#pragma unroll
        for (int d = 0; d < 4; ++d)
#pragma unroll
          for (int rr = 0; rr < 4; ++rr) {
            float4v c;
            c[0] = o[d][4 * rr + 0]; c[1] = o[d][4 * rr + 1];
            c[2] = o[d][4 * rr + 2]; c[3] = o[d][4 * rr + 3];
            const int cidx = 4 * (d * 4 + rr);
            *(float4v*)&Sf[sl * 4096 + ((lane * 64 + cidx) ^ ((lane & 7) << 2))] = c;
          }
      }
      asm volatile("s_waitcnt lgkmcnt(0)" ::: "memory");
      __builtin_amdgcn_s_barrier();
      if ((w >> 2) == round && kh == 0) {
        const int sl = j & 1;
#pragma unroll
        for (int d = 0; d < 4; ++d)
#pragma unroll
          for (int rr = 0; rr < 4; ++rr) {
            const int cidx = 4 * (d * 4 + rr);
            const float4v c =
                *(const float4v*)&Sf[sl * 4096 + ((lane * 64 + cidx) ^ ((lane & 7) << 2))];
            o[d][4 * rr + 0] += c[0]; o[d][4 * rr + 1] += c[1];
            o[d][4 * rr + 2] += c[2]; o[d][4 * rr + 3] += c[3];
          }
      }
      __builtin_amdgcn_s_barrier();
    }
    // (3) even waves: normalize + transposed bf16 write to Os
    u16* Os = &SMEM[49152];                    // [128][128] u16, swizzled
    if (kh == 0) {
      const float inv_l = 1.0f / lC;
      const int rl = 32 * j + l31;
#pragma unroll
      for (int d = 0; d < 4; ++d)
#pragma unroll
        for (int r = 0; r < 16; r += 2) {
          const int dd = 32 * d + (r & 3) + 8 * (r >> 2) + 4 * hi;
          const unsigned pr = cvtpk_bf16(o[d][r] * inv_l, o[d][r + 1] * inv_l);
          *(unsigned*)&Os[(rl * 128 + dd) ^ ((rl & 7) << 3)] = pr;
        }
    }
    asm volatile("s_waitcnt lgkmcnt(0)" ::: "memory");
    __builtin_amdgcn_s_barrier();
    // (4) coalesced store, all 8 waves
    {
      const int rr = t >> 2, cb = (t & 3) * 32;
      const size_t ob =
          ((size_t)(bb * 2048 + qt * 128 + rr)) * 2048 + h * 128 + cb;
#pragma unroll
      for (int p = 0; p < 4; ++p)
        *(u16x8*)&Ctx[ob + 8 * p] =
            *(const u16x8*)&Os[(rr * 128 + cb + 8 * p) ^ ((rr & 7) << 3)];
    }
    asm volatile("s_waitcnt lgkmcnt(0)" ::: "memory");
    __builtin_amdgcn_s_barrier();
  }
}

// ---------------------------------------------------------------------------
extern "C" void kernel_launch(void* const* d_in, const int* in_sizes, int n_in,
                              void* d_out, int out_size, void* d_ws, size_t ws_size,
                              hipStream_t stream) {
  const float* x  = (const float*)d_in[0];
  const float* Wq = (const float*)d_in[1];
  const float* Wk = (const float*)d_in[2];
  const float* Wv = (const float*)d_in[3];
  const float* Wo = (const float*)d_in[4];
  float* out = (float*)d_out;

  char* ws = (char*)d_ws;
  size_t off = 0;
  auto alloc = [&](size_t bytes) {
    char* p = ws + off;
    off += (bytes + 255) & ~(size_t)255;
    return p;
  };
  const size_t XE = (size_t)4096 * 2048;   // B*S x H elements
  const size_t WE = (size_t)2048 * 2048;

  u16* xh  = (u16*)alloc(XE * 2);
  u16* xl  = (u16*)alloc(XE * 2);
  u16* Wqh = (u16*)alloc(WE * 2);
  u16* Wql = (u16*)alloc(WE * 2);
  u16* Wkh = (u16*)alloc(WE * 2);
  u16* Wkl = (u16*)alloc(WE * 2);
  u16* Wvh = (u16*)alloc(WE * 2);
  u16* Woh = (u16*)alloc(WE * 2);
  u16* Qhb = (u16*)alloc(XE * 2);
  u16* Qlb = (u16*)alloc(XE * 2);
  u16* Khb = (u16*)alloc(XE * 2);
  u16* Klb = (u16*)alloc(XE * 2);
  u16* Vtb = (u16*)alloc(XE * 2);   // V^T: [2048 dims][4096 seq]
  u16* Ctxb = (u16*)alloc(XE * 2);
  float* cosT = (float*)alloc((size_t)2048 * 64 * 4);
  float* sinT = (float*)alloc((size_t)2048 * 64 * 4);
  (void)ws_size;  // requires ~170 MB of workspace
  (void)in_sizes; (void)n_in; (void)out_size;

  // 1) fused precision split + RoPE tables
  split_all<<<dim3(4096, 6), 256, 0, stream>>>(
      x, Wq, Wk, Wv, Wo, xh, xl, Wqh, Wql, Wkh, Wkl, Wvh, Woh);
  rope_tab<<<512, 256, 0, stream>>>(cosT, sinT);

  // 2) fused Q+K projection (shared A staging, shared RoPE tables)
  gemm_qk<<<dim3(16, 16), 512, 0, stream>>>(
      xh, xl, Wqh, Wql, Wkh, Wkl, Qhb, Qlb, Khb, Klb, cosT, sinT,
      11.313708498984760f, 4096, 2048, 2048);
  // V^T = Wv * x^T :  A=Wv (M=2048 dims), B=x (N=4096 seq)
  gemm1k<2, 32><<<dim3(32, 8), 512, 0, stream>>>(
      Wvh, xh, nullptr, Vtb, 2048, 4096, 2048);

  // 3) causal flash attention (de-duped task map, k-split wave pairs)
  attn<<<dim3(8, 16, 2), 512, 0, stream>>>(Qhb, Qlb, Khb, Klb, Vtb, Ctxb);

  // 4) output projection -> fp32 d_out
  gemm1k<0, 16><<<dim3(16, 16), 512, 0, stream>>>(
      Ctxb, Woh, out, nullptr, 4096, 2048, 2048);
}